// Round 9
// baseline (771.691 us; speedup 1.0000x reference)
//
#include <hip/hip_runtime.h>
#include <hip/hip_bf16.h>
#include <cstddef>

typedef __hip_bfloat16 bf16;
typedef __attribute__((ext_vector_type(8))) short short8;
typedef __attribute__((ext_vector_type(4))) float float4v;
typedef __attribute__((ext_vector_type(4))) unsigned short ushort4v;

static __device__ __forceinline__ float b2f(bf16 v) { return __bfloat162float(v); }
static __device__ __forceinline__ float bits2f(unsigned int u) { return __uint_as_float(u); }
static __device__ __forceinline__ unsigned short f2bfbits(float f) {
  bf16 h = __float2bfloat16(f);
  return *reinterpret_cast<unsigned short*>(&h);
}
static __device__ __forceinline__ float ld_any(const void* p, long i, int flag) {
  return flag ? b2f(((const bf16*)p)[i]) : ((const float*)p)[i];
}
static __device__ __forceinline__ void unpack_u4(uint4 u, float* f) {
  f[0] = bits2f(u.x << 16); f[1] = bits2f(u.x & 0xffff0000u);
  f[2] = bits2f(u.y << 16); f[3] = bits2f(u.y & 0xffff0000u);
  f[4] = bits2f(u.z << 16); f[5] = bits2f(u.z & 0xffff0000u);
  f[6] = bits2f(u.w << 16); f[7] = bits2f(u.w & 0xffff0000u);
}

// --------------------------------------------------------- dtype detection
__global__ void detect_dtype_kernel(const void* __restrict__ x, int* __restrict__ flag) {
  __shared__ int ok;
  if (threadIdx.x == 0) ok = 1;
  __syncthreads();
  float v = b2f(((const bf16*)x)[threadIdx.x]);
  if (!(v >= 0.f && v <= 1.0009765625f)) ok = 0;
  __syncthreads();
  if (threadIdx.x == 0) *flag = ok;
}

// ---------------------------------------------------------------- utilities
__global__ void zero2_kernel(float* p) {
  if (threadIdx.x < 2) p[threadIdx.x] = 0.f;
}

// zero only the 1-wide halo ring of up to 3 same-shape padded NHWC buffers
__global__ void zero_halo(bf16* p0, bf16* p1, bf16* p2, int np,
                          int H, int W, int C8, long imgS, int nimg, int gpi) {
  int tid = blockIdx.x * 256 + threadIdx.x;
  int total = nimg * gpi;
  int which = tid / total;
  if (which >= np) return;
  int r = tid - which * total;
  int img = r / gpi, g = r % gpi;
  int pos = g / C8, c8 = g % C8;
  int row, col;
  if (pos < W) { row = 0; col = pos; }
  else if (pos < 2 * W) { row = H - 1; col = pos - W; }
  else { int s = pos - 2 * W; row = 1 + (s >> 1); col = (s & 1) ? (W - 1) : 0; }
  bf16* base = (which == 0) ? p0 : ((which == 1) ? p1 : p2);
  uint4* dst = (uint4*)(base + (long)img * imgS + ((long)row * W + col) * (C8 * 8) + (long)c8 * 8);
  *dst = uint4{0u, 0u, 0u, 0u};
}

// all 6 conv biases -> one fp32 buffer [0:64|64:192|192:320|320:448|448:512|512:515]
__global__ void conv_bias_all(const void* s2, const void* s4, const void* s6,
                              const void* s10, const void* s12, const void* s14,
                              float* __restrict__ dst, const int* __restrict__ flag) {
  int i = blockIdx.x * 256 + threadIdx.x;
  if (i >= 515) return;
  int fl = *flag;
  const void* s; int off;
  if (i < 64)       { s = s2;  off = i; }
  else if (i < 192) { s = s4;  off = i - 64; }
  else if (i < 320) { s = s6;  off = i - 192; }
  else if (i < 448) { s = s10; off = i - 320; }
  else if (i < 512) { s = s12; off = i - 448; }
  else              { s = s14; off = i - 512; }
  dst[i] = ld_any(s, off, fl);
}

// both codebooks -> contiguous bf16 [1024][128]
__global__ void conv_emb(const void* __restrict__ sT, const void* __restrict__ sB,
                         bf16* __restrict__ dst, const int* __restrict__ flag) {
  int i = blockIdx.x * 256 + threadIdx.x;   // 131072
  int fl = *flag;
  const void* s = (i < 65536) ? sT : sB;
  int off = i & 65535;
  dst[i] = fl ? ((const bf16*)s)[off] : __float2bfloat16(((const float*)s)[off]);
}

__global__ void embsq2(const bf16* __restrict__ embTB, float* __restrict__ sqAll) {
  int k = blockIdx.x * blockDim.x + threadIdx.x;
  if (k >= 1024) return;
  float s = 0.f;
  const bf16* e = embTB + (long)k * 128;
  for (int c = 0; c < 128; ++c) { float v = b2f(e[c]); s = fmaf(v, v, s); }
  sqAll[k] = s;
}

// conv1 weights [64][3][4][4] -> [co][k] bf16, K padded 48->64 with zeros
__global__ void rp_c1w(const void* __restrict__ src, bf16* __restrict__ dst,
                       const int* __restrict__ flag) {
  int i = blockIdx.x * blockDim.x + threadIdx.x;   // 64*64
  if (i >= 4096) return;
  int co = i >> 6, k = i & 63;
  float v = (k < 48) ? ld_any(src, co * 48 + k, *flag) : 0.f;
  dst[i] = __float2bfloat16(v);
}

// weights OIHW [CO][CI][4][4] -> [tap=kh*4+kw][co][ci] bf16
template <int CO, int CI>
__global__ void rp_conv_w(const void* __restrict__ src, bf16* __restrict__ dst,
                          const int* __restrict__ flag) {
  const int N = CO * CI * 16;
  int i = blockIdx.x * blockDim.x + threadIdx.x;
  if (i >= N) return;
  int co = i / (CI * 16);
  int rem = i % (CI * 16);
  int ci = rem >> 4;
  int k = rem & 15;
  dst[((long)k * CO + co) * CI + ci] = __float2bfloat16(ld_any(src, i, *flag));
}

// convT weights [CI][CO][4][4] -> [class pq][tap st][co][ci] bf16
template <int CI, int CO>
__global__ void rp_convt_w(const void* __restrict__ src, bf16* __restrict__ dst,
                           const int* __restrict__ flag) {
  const int N = CI * CO * 16;
  int i = blockIdx.x * blockDim.x + threadIdx.x;
  if (i >= N) return;
  int ci = i / (CO * 16);
  int rem = i % (CO * 16);
  int co = rem >> 4;
  int k = rem & 15;
  int kh = k >> 2, kw = k & 3;
  int p = (kh + 1) & 1, s = (kh - 1 + p) >> 1;
  int q = (kw + 1) & 1, t = (kw - 1 + q) >> 1;
  long d = (((long)(p * 2 + q) * 4 + (s * 2 + t)) * CO + co) * CI + ci;
  dst[d] = __float2bfloat16(ld_any(src, i, *flag));
}

// final convT weights [64ci][3co][4][4] -> A[m=cls*4+co][d=dy*3+dx][64ci]
__global__ void rp_finw(const void* __restrict__ src, bf16* __restrict__ dst,
                        const int* __restrict__ flag) {
  int i = blockIdx.x * blockDim.x + threadIdx.x;   // 16*576 = 9216
  if (i >= 9216) return;
  int m = i / 576, rem = i % 576;
  int d = rem >> 6, ci = rem & 63;
  int cls = m >> 2, co = m & 3;
  int p = cls >> 1, q = cls & 1;
  int dy = d / 3, dx = d % 3;
  int s = p - dy + 1, t = q - dx + 1;
  float v = 0.f;
  if (co < 3 && s >= 0 && s <= 1 && t >= 0 && t <= 1) {
    int kh = 2 * s + 1 - p, kw = 2 * t + 1 - q;
    v = ld_any(src, ci * 48 + co * 16 + kh * 4 + kw, *flag);
  }
  dst[i] = __float2bfloat16(v);
}

// -------------------- conv1 as GEMM: im2col (K padded to 64) + MFMA GEMM
__global__ __launch_bounds__(256) void im2col1(const void* __restrict__ x,
                                               const int* __restrict__ flag,
                                               bf16* __restrict__ col) {
  int tid = blockIdx.x * 256 + threadIdx.x;   // 16*128*128
  int ow = tid & 127; int t = tid >> 7;
  int oh = t & 127; int b = t >> 7;
  int fl = *flag;
  int ih0 = oh * 2 - 1, iw0 = ow * 2 - 1;
  unsigned short vals[64];
  #pragma unroll
  for (int j = 48; j < 64; ++j) vals[j] = 0;
  #pragma unroll
  for (int ci = 0; ci < 3; ++ci) {
    long pbase = ((long)(b * 3 + ci)) << 16;
    #pragma unroll
    for (int kh = 0; kh < 4; ++kh) {
      int ih = ih0 + kh;
      bool okh = (unsigned)ih < 256u;
      long rbase = pbase + ((long)ih << 8);
      #pragma unroll
      for (int kw = 0; kw < 4; ++kw) {
        int iw = iw0 + kw;
        float v = (okh && (unsigned)iw < 256u) ? ld_any(x, rbase + iw, fl) : 0.f;
        vals[ci * 16 + kh * 4 + kw] = f2bfbits(v);
      }
    }
  }
  uint4* dst = (uint4*)(col + (long)tid * 64);
  const uint4* s = (const uint4*)vals;
  #pragma unroll
  for (int j = 0; j < 8; ++j) dst[j] = s[j];
}

// M=64 (co), K=64, N=262144 (positions); bias+relu; store padded NHWC
__global__ __launch_bounds__(256) void gemm1(const bf16* __restrict__ col,
                                             const bf16* __restrict__ w,
                                             const float* __restrict__ bias,
                                             bf16* __restrict__ act1p) {
  const int lane = threadIdx.x & 63, wv = threadIdx.x >> 6;
  const int wm = wv & 1, wn = wv >> 1;
  const int ln = lane & 15, quad = lane >> 4;
  const int n0 = blockIdx.x * 128 + wn * 64;
  float4v acc[2][4];
  #pragma unroll
  for (int i = 0; i < 2; ++i)
    #pragma unroll
    for (int j = 0; j < 4; ++j) acc[i][j] = {0.f, 0.f, 0.f, 0.f};
  #pragma unroll
  for (int kc = 0; kc < 2; ++kc) {
    const bf16* wk = w + (wm * 32 + ln) * 64 + kc * 32 + quad * 8;
    short8 a0 = *(const short8*)(wk);
    short8 a1 = *(const short8*)(wk + 16 * 64);
    #pragma unroll
    for (int bf = 0; bf < 4; ++bf) {
      short8 bv = *(const short8*)(col + (long)(n0 + bf * 16 + ln) * 64 + kc * 32 + quad * 8);
      acc[0][bf] = __builtin_amdgcn_mfma_f32_16x16x32_bf16(a0, bv, acc[0][bf], 0, 0, 0);
      acc[1][bf] = __builtin_amdgcn_mfma_f32_16x16x32_bf16(a1, bv, acc[1][bf], 0, 0, 0);
    }
  }
  #pragma unroll
  for (int mf = 0; mf < 2; ++mf) {
    int coB = wm * 32 + mf * 16 + quad * 4;
    float4v bv4 = *(const float4v*)(bias + coB);
    #pragma unroll
    for (int bf = 0; bf < 4; ++bf) {
      int n = n0 + bf * 16 + ln;
      int ow = n & 127; int t2 = n >> 7;
      int oh = t2 & 127; int b = t2 >> 7;
      long oaddr = ((long)(b * 130 + oh + 1) * 130 + ow + 1) * 64 + coB;
      float4v v = acc[mf][bf];
      ushort4v o;
      #pragma unroll
      for (int e = 0; e < 4; ++e) o[e] = f2bfbits(fmaxf(v[e] + bv4[e], 0.f));
      *(ushort4v*)(act1p + oaddr) = o;
    }
  }
}

// ------------------------------------------- MFMA implicit-GEMM tap conv
// NBF = B-frags per wave (wave tile M32 x N(16*NBF)). Class (for S=1
// multi-class launches) decoded as cls = blockIdx.x >> nxb; weights are
// per-class chunks of NT*COUT*CINT; output offset (p+1)*po + (q+1)*qo.
template <int COUT, int CINT, int TC, int S, int NT, int INC, int NBF>
__global__ __launch_bounds__(256) void mfma_conv(
    const bf16* __restrict__ in1, const bf16* __restrict__ in2,
    long inImgS, int inRowS,
    const bf16* __restrict__ w, const float* __restrict__ bias,
    bf16* __restrict__ outp, long outImgS, int oRS, int oCS,
    int nxb, long po, long qo) {
  constexpr int TR = (2 * NBF * 16) / TC;
  constexpr int KC = CINT / 32;
  constexpr int KSPLIT = (CINT > INC) ? (INC / 32) : KC;
  const int lane = threadIdx.x & 63;
  const int wv = threadIdx.x >> 6;
  const int wm = wv & 1, wn = wv >> 1;
  const int ln = lane & 15, quad = lane >> 4;
  const int cls = blockIdx.x >> nxb;
  const int xb = blockIdx.x & ((1u << nxb) - 1u);
  const int mTile = blockIdx.y * 64;
  const int oh0 = xb * TR;
  const int b = blockIdx.z;
  const int p = cls >> 1, q = cls & 1;
  const bf16* wcl = w + (long)cls * (NT * COUT * CINT);
  const long ooff = (long)(p + 1) * po + (long)(q + 1) * qo;

  long posOff[NBF];
  int rr[NBF], cc[NBF];
  #pragma unroll
  for (int bf = 0; bf < NBF; ++bf) {
    int n = wn * (NBF * 16) + bf * 16 + ln;
    int r = n / TC, c = n % TC;
    rr[bf] = r; cc[bf] = c;
    posOff[bf] = (long)(S * (oh0 + r)) * inRowS + (long)(S * c) * INC;
  }
  const bf16* inb1 = in1 + (long)b * inImgS;
  const bf16* inb2 = in2 + (long)b * inImgS;

  float4v acc[2][NBF];
  #pragma unroll
  for (int i = 0; i < 2; ++i)
    #pragma unroll
    for (int j = 0; j < NBF; ++j) acc[i][j] = {0.f, 0.f, 0.f, 0.f};

  for (int t = 0; t < NT; ++t) {
    int dy, dx;
    if (S == 2) { dy = t >> 2; dx = t & 3; }
    else        { dy = p - (t >> 1) + 1; dx = q - (t & 1) + 1; }
    const long tapOff = (long)dy * inRowS + (long)dx * INC;
    const bf16* wt = wcl + (long)t * COUT * CINT;
    const bf16* wk0 = wt + (long)(mTile + wm * 32 + ln) * CINT + quad * 8;
    #pragma unroll
    for (int kc = 0; kc < KC; ++kc) {
      short8 a0 = *(const short8*)(wk0 + kc * 32);
      short8 a1 = *(const short8*)(wk0 + kc * 32 + 16 * CINT);
      const bf16* bp = (kc < KSPLIT) ? inb1 : inb2;
      int kOff = (kc < KSPLIT ? kc : kc - KSPLIT) * 32 + quad * 8;
      #pragma unroll
      for (int bf = 0; bf < NBF; ++bf) {
        short8 bv = *(const short8*)(bp + posOff[bf] + tapOff + kOff);
        acc[0][bf] = __builtin_amdgcn_mfma_f32_16x16x32_bf16(a0, bv, acc[0][bf], 0, 0, 0);
        acc[1][bf] = __builtin_amdgcn_mfma_f32_16x16x32_bf16(a1, bv, acc[1][bf], 0, 0, 0);
      }
    }
  }

  bf16* outb = outp + (long)b * outImgS + ooff;
  #pragma unroll
  for (int mf = 0; mf < 2; ++mf) {
    int coB = mTile + wm * 32 + mf * 16 + quad * 4;
    float4v bv4 = *(const float4v*)(bias + coB);
    #pragma unroll
    for (int bf = 0; bf < NBF; ++bf) {
      float4v v = acc[mf][bf];
      ushort4v o;
      #pragma unroll
      for (int e = 0; e < 4; ++e)
        o[e] = f2bfbits(fmaxf(v[e] + bv4[e], 0.f));
      long oaddr = (long)(oh0 + rr[bf]) * oRS + (long)cc[bf] * oCS + coB;
      *(ushort4v*)(outb + oaddr) = o;
    }
  }
}

// ---------------------------------------------------- VQ via MFMA GEMM
__global__ __launch_bounds__(256) void vq_mfma(
    const bf16* __restrict__ z, long zImgS, int zRowS,
    const bf16* __restrict__ emb, const float* __restrict__ embsq,
    bf16* __restrict__ zq, long qImgS, int qRowS,
    float* __restrict__ loss_acc, int wb, int hwb) {
  const int lane = threadIdx.x & 63, wv = threadIdx.x >> 6;
  const int ln = lane & 15, quad = lane >> 4;
  const int base = blockIdx.x * 256 + wv * 64;

  short8 bfrag[4][4];
  #pragma unroll
  for (int bf = 0; bf < 4; ++bf) {
    int n = base + bf * 16 + ln;
    int b = n >> hwb;
    int rem = n & ((1 << hwb) - 1);
    int y = rem >> wb, x = rem & ((1 << wb) - 1);
    const bf16* zrow = z + (long)b * zImgS + (long)y * zRowS + (long)x * 128;
    #pragma unroll
    for (int kc = 0; kc < 4; ++kc)
      bfrag[bf][kc] = *(const short8*)(zrow + kc * 32 + quad * 8);
  }

  float best0 = 3.4e38f, best1 = 3.4e38f, best2 = 3.4e38f, best3 = 3.4e38f;
  int bk0 = 0, bk1 = 0, bk2 = 0, bk3 = 0;
  for (int ct = 0; ct < 32; ++ct) {
    const bf16* erow = emb + (long)(ct * 16 + ln) * 128 + quad * 8;
    short8 a0 = *(const short8*)(erow);
    short8 a1 = *(const short8*)(erow + 32);
    short8 a2 = *(const short8*)(erow + 64);
    short8 a3 = *(const short8*)(erow + 96);
    float4v sq4 = *(const float4v*)(embsq + ct * 16 + quad * 4);
    #pragma unroll
    for (int bf = 0; bf < 4; ++bf) {
      float4v acc = {0.f, 0.f, 0.f, 0.f};
      acc = __builtin_amdgcn_mfma_f32_16x16x32_bf16(a0, bfrag[bf][0], acc, 0, 0, 0);
      acc = __builtin_amdgcn_mfma_f32_16x16x32_bf16(a1, bfrag[bf][1], acc, 0, 0, 0);
      acc = __builtin_amdgcn_mfma_f32_16x16x32_bf16(a2, bfrag[bf][2], acc, 0, 0, 0);
      acc = __builtin_amdgcn_mfma_f32_16x16x32_bf16(a3, bfrag[bf][3], acc, 0, 0, 0);
      int kb = ct * 16 + quad * 4;
      #pragma unroll
      for (int r = 0; r < 4; ++r) {
        float s = fmaf(-2.f, acc[r], sq4[r]);
        if (bf == 0) { if (s < best0) { best0 = s; bk0 = kb + r; } }
        if (bf == 1) { if (s < best1) { best1 = s; bk1 = kb + r; } }
        if (bf == 2) { if (s < best2) { best2 = s; bk2 = kb + r; } }
        if (bf == 3) { if (s < best3) { best3 = s; bk3 = kb + r; } }
      }
    }
  }
  float bs[4] = {best0, best1, best2, best3};
  int bk[4] = {bk0, bk1, bk2, bk3};
  #pragma unroll
  for (int bf = 0; bf < 4; ++bf) {
    #pragma unroll
    for (int m = 16; m <= 32; m <<= 1) {
      float os = __shfl_xor(bs[bf], m, 64);
      int ok = __shfl_xor(bk[bf], m, 64);
      if (os < bs[bf] || (os == bs[bf] && ok < bk[bf])) { bs[bf] = os; bk[bf] = ok; }
    }
  }
  int myk = (quad == 0) ? bk[0] : (quad == 1) ? bk[1] : (quad == 2) ? bk[2] : bk[3];
  int n = base + quad * 16 + ln;
  int b = n >> hwb;
  int rem = n & ((1 << hwb) - 1);
  int y = rem >> wb, x = rem & ((1 << wb) - 1);
  const uint4* zr = (const uint4*)(z + (long)b * zImgS + (long)y * zRowS + (long)x * 128);
  uint4* qr = (uint4*)(zq + (long)b * qImgS + (long)y * qRowS + (long)x * 128);
  const uint4* er = (const uint4*)(emb + (long)myk * 128);
  float lsum = 0.f;
  #pragma unroll
  for (int j = 0; j < 16; ++j) {
    uint4 ue = er[j];
    uint4 uz = zr[j];
    qr[j] = ue;
    float ev[8], zv[8];
    unpack_u4(ue, ev);
    unpack_u4(uz, zv);
    #pragma unroll
    for (int e = 0; e < 8; ++e) {
      float dv = ev[e] - zv[e];
      lsum = fmaf(dv, dv, lsum);
    }
  }
  for (int o = 32; o > 0; o >>= 1) lsum += __shfl_down(lsum, o, 64);
  if (lane == 0) atomicAdd(loss_acc, lsum);
}

// --------------------- final convT(64->3)+sigmoid via class-packed MFMA
__global__ __launch_bounds__(256) void final_convt_mfma(
    const bf16* __restrict__ hp, const bf16* __restrict__ wfin,
    const float* __restrict__ bf_, float* __restrict__ out) {
  const int lane = threadIdx.x & 63, wv = threadIdx.x >> 6;
  const int ln = lane & 15, quad = lane >> 4;
  const int base = blockIdx.x * 256 + wv * 64;   // 262144 positions total

  short8 afr[18];
  #pragma unroll
  for (int kc = 0; kc < 18; ++kc)
    afr[kc] = *(const short8*)(wfin + ln * 576 + kc * 32 + quad * 8);

  float4v acc[4];
  #pragma unroll
  for (int bf = 0; bf < 4; ++bf) acc[bf] = {0.f, 0.f, 0.f, 0.f};

  #pragma unroll
  for (int bf = 0; bf < 4; ++bf) {
    int n = base + bf * 16 + ln;
    int xx = n & 127, y = (n >> 7) & 127, b = n >> 14;
    const bf16* hb = hp + (long)b * 1081600 + (long)y * 8320 + (long)xx * 64;
    #pragma unroll
    for (int kc = 0; kc < 18; ++kc) {
      int d = kc >> 1;
      const bf16* bp = hb + (long)(d / 3) * 8320 + (d % 3) * 64 + (kc & 1) * 32 + quad * 8;
      short8 bv = *(const short8*)bp;
      acc[bf] = __builtin_amdgcn_mfma_f32_16x16x32_bf16(afr[kc], bv, acc[bf], 0, 0, 0);
    }
  }

  const int p = quad >> 1, q = quad & 1;
  float b0 = bf_[0], b1 = bf_[1], b2 = bf_[2];
  #pragma unroll
  for (int bf = 0; bf < 4; ++bf) {
    int n = base + bf * 16 + ln;
    int xx = n & 127, y = (n >> 7) & 127, b = n >> 14;
    long ob = (long)b * 196608 + (long)(2 * y + p) * 256 + (2 * xx + q);
    float v0 = acc[bf][0] + b0, v1 = acc[bf][1] + b1, v2 = acc[bf][2] + b2;
    out[ob]          = 1.f / (1.f + expf(-v0));
    out[ob + 65536]  = 1.f / (1.f + expf(-v1));
    out[ob + 131072] = 1.f / (1.f + expf(-v2));
  }
}

__global__ void finalize_loss_kernel(const float* __restrict__ lacc, float* __restrict__ out) {
  if (threadIdx.x == 0) {
    float lt = lacc[0] * (1.5f / 2097152.f);
    float lb = lacc[1] * (1.5f / 8388608.f);
    *out = lt + lb;
  }
}

// ------------------------------------------------------------------ launch
extern "C" void kernel_launch(void* const* d_in, const int* in_sizes, int n_in,
                              void* d_out, int out_size, void* d_ws, size_t ws_size,
                              hipStream_t stream) {
  float* out = (float*)d_out;
  char* base = (char*)d_ws;
  size_t off = 0;
  auto alloc = [&](size_t bytes) {
    void* pp = base + off;
    off = (off + bytes + 255) & ~(size_t)255;
    return pp;
  };

  int* flag = (int*)alloc(256);
  float* biasAll = (float*)alloc(515 * 4);
  float* beB1f = biasAll + 0;
  float* beB2f = biasAll + 64;
  float* beTf  = biasAll + 192;
  float* bdTf  = biasAll + 320;
  float* bd1f  = biasAll + 448;
  float* bd2f  = biasAll + 512;
  float* sqAll = (float*)alloc(1024 * 4);
  float* sqT = sqAll, *sqB = sqAll + 512;
  float* lacc = (float*)alloc(2 * 4);
  bf16* Wc1  = (bf16*)alloc((size_t)4096 * 2);
  bf16* Wt2  = (bf16*)alloc((size_t)131072 * 2);
  bf16* Wtt  = (bf16*)alloc((size_t)262144 * 2);
  bf16* Wdt  = (bf16*)alloc((size_t)262144 * 2);
  bf16* Wd1  = (bf16*)alloc((size_t)262144 * 2);
  bf16* Wfin = (bf16*)alloc((size_t)9216 * 2);
  bf16* embTB = (bf16*)alloc((size_t)131072 * 2);
  bf16* embT = embTB, *embB = embTB + 65536;
  bf16* colb = (bf16*)alloc((size_t)16777216 * 2);   // im2col [262144][64]
  bf16* act1p = (bf16*)alloc((size_t)17305600 * 2);  // [16][130][130][64]
  bf16* zbp   = (bf16*)alloc((size_t)8921088 * 2);   // [16][66][66][128]
  bf16* zqtp  = (bf16*)alloc((size_t)2367488 * 2);   // [16][34][34][128]
  bf16* eup   = (bf16*)alloc((size_t)8921088 * 2);   // [16][66][66][128]
  bf16* fqp   = (bf16*)alloc((size_t)8921088 * 2);   // [16][66][66][128]
  bf16* hp    = (bf16*)alloc((size_t)17305600 * 2);  // [16][130][130][64]
  bf16* ztp   = (bf16*)alloc((size_t)2097152 * 2);   // [16][32][32][128]

  detect_dtype_kernel<<<1, 256, 0, stream>>>(d_in[0], flag);
  zero2_kernel<<<1, 64, 0, stream>>>(lacc);

  // halo-only zeroing (interiors are fully overwritten by their producers)
  zero_halo<<<517, 256, 0, stream>>>(act1p, hp, nullptr, 2, 130, 130, 8, 1081600, 16, 4128);
  zero_halo<<<781, 256, 0, stream>>>(zbp, eup, fqp, 3, 66, 66, 16, 557568, 16, 4160);
  zero_halo<<<132, 256, 0, stream>>>(zqtp, nullptr, nullptr, 1, 34, 34, 16, 147968, 16, 2112);

  // converts / repacks
  conv_bias_all<<<3, 256, 0, stream>>>(d_in[2], d_in[4], d_in[6], d_in[10],
                                       d_in[12], d_in[14], biasAll, flag);
  conv_emb<<<512, 256, 0, stream>>>(d_in[7], d_in[8], embTB, flag);
  embsq2<<<4, 256, 0, stream>>>(embTB, sqAll);
  rp_c1w<<<16, 256, 0, stream>>>(d_in[1], Wc1, flag);
  rp_conv_w<128, 64><<<512, 256, 0, stream>>>(d_in[3], Wt2, flag);
  rp_conv_w<128, 128><<<1024, 256, 0, stream>>>(d_in[5], Wtt, flag);
  rp_convt_w<128, 128><<<1024, 256, 0, stream>>>(d_in[9], Wdt, flag);
  rp_convt_w<256, 64><<<1024, 256, 0, stream>>>(d_in[11], Wd1, flag);
  rp_finw<<<36, 256, 0, stream>>>(d_in[13], Wfin, flag);

  // encoder: conv1 = im2col + MFMA GEMM
  im2col1<<<1024, 256, 0, stream>>>(d_in[0], flag, colb);
  gemm1<<<2048, 256, 0, stream>>>(colb, Wc1, beB1f, act1p);
  // conv2: NBF=2, TR=1 -> 2048 blocks
  mfma_conv<128, 64, 64, 2, 16, 64, 2><<<dim3(64, 2, 16), 256, 0, stream>>>(
      act1p, act1p, 1081600, 8320, Wt2, beB2f, zbp + 8576, 557568, 8448, 128, 30, 0, 0);
  // conv_t: NBF=2, TR=2 -> 512 blocks
  mfma_conv<128, 128, 32, 2, 16, 128, 2><<<dim3(16, 2, 16), 256, 0, stream>>>(
      zbp, zbp, 557568, 8448, Wtt, beTf, ztp, 131072, 4096, 128, 30, 0, 0);

  // VQ top (16384 positions)
  vq_mfma<<<64, 256, 0, stream>>>(ztp, 131072, 4096, embT, sqT,
                                  zqtp + 4480, 147968, 4352, lacc + 0, 5, 10);

  // decoder_top upsample: 4 classes in one launch (nxb=4: 16 x-blocks/class)
  mfma_conv<128, 128, 32, 1, 4, 128, 2><<<dim3(64, 2, 16), 256, 0, stream>>>(
      zqtp, zqtp, 147968, 4352, Wdt, bdTf, eup, 557568, 16896, 256, 4, 8448, 128);

  // VQ bottom (65536 positions)
  vq_mfma<<<256, 256, 0, stream>>>(zbp + 8576, 557568, 8448, embB, sqB,
                                   fqp + 8576, 557568, 8448, lacc + 1, 6, 12);

  // decoder conv d1: 4 classes in one launch (nxb=6: 64 x-blocks/class)
  mfma_conv<64, 256, 64, 1, 4, 128, 2><<<dim3(256, 1, 16), 256, 0, stream>>>(
      fqp, eup, 557568, 8448, Wd1, bd1f, hp, 1081600, 16640, 128, 6, 8320, 64);

  // final convT + sigmoid via MFMA -> fp32 NCHW output
  final_convt_mfma<<<1024, 256, 0, stream>>>(hp, Wfin, bd2f, out);
  finalize_loss_kernel<<<1, 64, 0, stream>>>(lacc, out + 3145728);
}

// Round 10
// 598.307 us; speedup vs baseline: 1.2898x; 1.2898x over previous
//
#include <hip/hip_runtime.h>
#include <hip/hip_bf16.h>
#include <cstddef>

typedef __hip_bfloat16 bf16;
typedef __attribute__((ext_vector_type(8))) short short8;
typedef __attribute__((ext_vector_type(4))) float float4v;
typedef __attribute__((ext_vector_type(4))) unsigned short ushort4v;

static __device__ __forceinline__ float b2f(bf16 v) { return __bfloat162float(v); }
static __device__ __forceinline__ float bits2f(unsigned int u) { return __uint_as_float(u); }
static __device__ __forceinline__ unsigned short f2bfbits(float f) {
  bf16 h = __float2bfloat16(f);
  return *reinterpret_cast<unsigned short*>(&h);
}
static __device__ __forceinline__ float ld_any(const void* p, long i, int flag) {
  return flag ? b2f(((const bf16*)p)[i]) : ((const float*)p)[i];
}
static __device__ __forceinline__ void unpack_u4(uint4 u, float* f) {
  f[0] = bits2f(u.x << 16); f[1] = bits2f(u.x & 0xffff0000u);
  f[2] = bits2f(u.y << 16); f[3] = bits2f(u.y & 0xffff0000u);
  f[4] = bits2f(u.z << 16); f[5] = bits2f(u.z & 0xffff0000u);
  f[6] = bits2f(u.w << 16); f[7] = bits2f(u.w & 0xffff0000u);
}

// --------------------------------------------------------- dtype detection
__global__ void detect_dtype_kernel(const void* __restrict__ x, int* __restrict__ flag) {
  __shared__ int ok;
  if (threadIdx.x == 0) ok = 1;
  __syncthreads();
  float v = b2f(((const bf16*)x)[threadIdx.x]);
  if (!(v >= 0.f && v <= 1.0009765625f)) ok = 0;
  __syncthreads();
  if (threadIdx.x == 0) *flag = ok;
}

// ---------------------------------------------------------------- utilities
__global__ void zero2_kernel(float* p) {
  if (threadIdx.x < 2) p[threadIdx.x] = 0.f;
}

// zero only the 1-wide halo ring of up to 3 same-shape padded NHWC buffers
__global__ void zero_halo(bf16* p0, bf16* p1, bf16* p2, int np,
                          int H, int W, int C8, long imgS, int nimg, int gpi) {
  int tid = blockIdx.x * 256 + threadIdx.x;
  int total = nimg * gpi;
  int which = tid / total;
  if (which >= np) return;
  int r = tid - which * total;
  int img = r / gpi, g = r % gpi;
  int pos = g / C8, c8 = g % C8;
  int row, col;
  if (pos < W) { row = 0; col = pos; }
  else if (pos < 2 * W) { row = H - 1; col = pos - W; }
  else { int s = pos - 2 * W; row = 1 + (s >> 1); col = (s & 1) ? (W - 1) : 0; }
  bf16* base = (which == 0) ? p0 : ((which == 1) ? p1 : p2);
  uint4* dst = (uint4*)(base + (long)img * imgS + ((long)row * W + col) * (C8 * 8) + (long)c8 * 8);
  *dst = uint4{0u, 0u, 0u, 0u};
}

// all 6 conv biases -> one fp32 buffer
__global__ void conv_bias_all(const void* s2, const void* s4, const void* s6,
                              const void* s10, const void* s12, const void* s14,
                              float* __restrict__ dst, const int* __restrict__ flag) {
  int i = blockIdx.x * 256 + threadIdx.x;
  if (i >= 515) return;
  int fl = *flag;
  const void* s; int off;
  if (i < 64)       { s = s2;  off = i; }
  else if (i < 192) { s = s4;  off = i - 64; }
  else if (i < 320) { s = s6;  off = i - 192; }
  else if (i < 448) { s = s10; off = i - 320; }
  else if (i < 512) { s = s12; off = i - 448; }
  else              { s = s14; off = i - 512; }
  dst[i] = ld_any(s, off, fl);
}

// both codebooks -> contiguous bf16 [1024][128]
__global__ void conv_emb(const void* __restrict__ sT, const void* __restrict__ sB,
                         bf16* __restrict__ dst, const int* __restrict__ flag) {
  int i = blockIdx.x * 256 + threadIdx.x;   // 131072
  int fl = *flag;
  const void* s = (i < 65536) ? sT : sB;
  int off = i & 65535;
  dst[i] = fl ? ((const bf16*)s)[off] : __float2bfloat16(((const float*)s)[off]);
}

__global__ void embsq2(const bf16* __restrict__ embTB, float* __restrict__ sqAll) {
  int k = blockIdx.x * blockDim.x + threadIdx.x;
  if (k >= 1024) return;
  float s = 0.f;
  const bf16* e = embTB + (long)k * 128;
  for (int c = 0; c < 128; ++c) { float v = b2f(e[c]); s = fmaf(v, v, s); }
  sqAll[k] = s;
}

// conv1 weights [64][3][4][4] -> [co][k] bf16, K padded 48->64 with zeros
__global__ void rp_c1w(const void* __restrict__ src, bf16* __restrict__ dst,
                       const int* __restrict__ flag) {
  int i = blockIdx.x * blockDim.x + threadIdx.x;   // 64*64
  if (i >= 4096) return;
  int co = i >> 6, k = i & 63;
  float v = (k < 48) ? ld_any(src, co * 48 + k, *flag) : 0.f;
  dst[i] = __float2bfloat16(v);
}

// weights OIHW [CO][CI][4][4] -> [tap=kh*4+kw][co][ci] bf16
template <int CO, int CI>
__global__ void rp_conv_w(const void* __restrict__ src, bf16* __restrict__ dst,
                          const int* __restrict__ flag) {
  const int N = CO * CI * 16;
  int i = blockIdx.x * blockDim.x + threadIdx.x;
  if (i >= N) return;
  int co = i / (CI * 16);
  int rem = i % (CI * 16);
  int ci = rem >> 4;
  int k = rem & 15;
  dst[((long)k * CO + co) * CI + ci] = __float2bfloat16(ld_any(src, i, *flag));
}

// convT weights [CI][CO][4][4] -> [class pq][tap st][co][ci] bf16
template <int CI, int CO>
__global__ void rp_convt_w(const void* __restrict__ src, bf16* __restrict__ dst,
                           const int* __restrict__ flag) {
  const int N = CI * CO * 16;
  int i = blockIdx.x * blockDim.x + threadIdx.x;
  if (i >= N) return;
  int ci = i / (CO * 16);
  int rem = i % (CO * 16);
  int co = rem >> 4;
  int k = rem & 15;
  int kh = k >> 2, kw = k & 3;
  int p = (kh + 1) & 1, s = (kh - 1 + p) >> 1;
  int q = (kw + 1) & 1, t = (kw - 1 + q) >> 1;
  long d = (((long)(p * 2 + q) * 4 + (s * 2 + t)) * CO + co) * CI + ci;
  dst[d] = __float2bfloat16(ld_any(src, i, *flag));
}

// [tg][co][ci] -> fragment order [((tg*MC+mc)*KC+kc)*2+j][ln][quad*8]
// co = mc*32 + j*16 + ln, ci = kc*32 + cl  (KC, MC powers of 2)
template <int MC, int KC>
__global__ void frag_pack(const bf16* __restrict__ src, bf16* __restrict__ dst, int total) {
  int i = blockIdx.x * 256 + threadIdx.x;
  if (i >= total) return;
  int low = i & 511;
  int ln = low >> 5, cl = low & 31;
  int c2 = i >> 9;
  int j = c2 & 1;
  int c3 = c2 >> 1;
  int kc = c3 & (KC - 1);
  int c4 = c3 / KC;
  int mc = c4 & (MC - 1);
  int tg = c4 / MC;
  int co = mc * 32 + j * 16 + ln;
  int ci = kc * 32 + cl;
  dst[i] = src[((long)tg * (MC * 32) + co) * (KC * 32) + ci];
}

// d1 weights [256ci][64co][4][4] -> frag [(((cls*4+t)*8+kc)*4+j)][ln][quad*8]
__global__ void rp_d1f(const void* __restrict__ src, bf16* __restrict__ dst,
                       const int* __restrict__ flag) {
  int i = blockIdx.x * 256 + threadIdx.x;   // 262144
  if (i >= 262144) return;
  int low = i & 511;
  int ln = low >> 5, cl = low & 31;
  int c2 = i >> 9;
  int j = c2 & 3;
  int kc = (c2 >> 2) & 7;
  int t = (c2 >> 5) & 3;
  int cls = c2 >> 7;
  int p = cls >> 1, q = cls & 1;
  int s = t >> 1, t2 = t & 1;
  int kh = 2 * s + 1 - p, kw = 2 * t2 + 1 - q;
  int co = j * 16 + ln, ci = kc * 32 + cl;
  dst[i] = __float2bfloat16(ld_any(src, (long)ci * 1024 + co * 16 + kh * 4 + kw, *flag));
}

// final convT weights [64ci][3co][4][4] -> A[m=cls*4+co][d=dy*3+dx][64ci]
__global__ void rp_finw(const void* __restrict__ src, bf16* __restrict__ dst,
                        const int* __restrict__ flag) {
  int i = blockIdx.x * blockDim.x + threadIdx.x;   // 16*576 = 9216
  if (i >= 9216) return;
  int m = i / 576, rem = i % 576;
  int d = rem >> 6, ci = rem & 63;
  int cls = m >> 2, co = m & 3;
  int p = cls >> 1, q = cls & 1;
  int dy = d / 3, dx = d % 3;
  int s = p - dy + 1, t = q - dx + 1;
  float v = 0.f;
  if (co < 3 && s >= 0 && s <= 1 && t >= 0 && t <= 1) {
    int kh = 2 * s + 1 - p, kw = 2 * t + 1 - q;
    v = ld_any(src, ci * 48 + co * 16 + kh * 4 + kw, *flag);
  }
  dst[i] = __float2bfloat16(v);
}

// -------------------- conv1 as GEMM: im2col (K padded to 64) + MFMA GEMM
__global__ __launch_bounds__(256) void im2col1(const void* __restrict__ x,
                                               const int* __restrict__ flag,
                                               bf16* __restrict__ col) {
  int tid = blockIdx.x * 256 + threadIdx.x;   // 16*128*128
  int ow = tid & 127; int t = tid >> 7;
  int oh = t & 127; int b = t >> 7;
  int fl = *flag;
  int ih0 = oh * 2 - 1, iw0 = ow * 2 - 1;
  unsigned short vals[64];
  #pragma unroll
  for (int j = 48; j < 64; ++j) vals[j] = 0;
  #pragma unroll
  for (int ci = 0; ci < 3; ++ci) {
    long pbase = ((long)(b * 3 + ci)) << 16;
    #pragma unroll
    for (int kh = 0; kh < 4; ++kh) {
      int ih = ih0 + kh;
      bool okh = (unsigned)ih < 256u;
      long rbase = pbase + ((long)ih << 8);
      #pragma unroll
      for (int kw = 0; kw < 4; ++kw) {
        int iw = iw0 + kw;
        float v = (okh && (unsigned)iw < 256u) ? ld_any(x, rbase + iw, fl) : 0.f;
        vals[ci * 16 + kh * 4 + kw] = f2bfbits(v);
      }
    }
  }
  uint4* dst = (uint4*)(col + (long)tid * 64);
  const uint4* s = (const uint4*)vals;
  #pragma unroll
  for (int j = 0; j < 8; ++j) dst[j] = s[j];
}

// M=64 (co), K=64, N=262144 (positions); bias+relu; store padded NHWC
__global__ __launch_bounds__(256) void gemm1(const bf16* __restrict__ col,
                                             const bf16* __restrict__ w,
                                             const float* __restrict__ bias,
                                             bf16* __restrict__ act1p) {
  const int lane = threadIdx.x & 63, wv = threadIdx.x >> 6;
  const int wm = wv & 1, wn = wv >> 1;
  const int ln = lane & 15, quad = lane >> 4;
  const int n0 = blockIdx.x * 128 + wn * 64;
  float4v acc[2][4];
  #pragma unroll
  for (int i = 0; i < 2; ++i)
    #pragma unroll
    for (int j = 0; j < 4; ++j) acc[i][j] = {0.f, 0.f, 0.f, 0.f};
  #pragma unroll
  for (int kc = 0; kc < 2; ++kc) {
    const bf16* wk = w + (wm * 32 + ln) * 64 + kc * 32 + quad * 8;
    short8 a0 = *(const short8*)(wk);
    short8 a1 = *(const short8*)(wk + 16 * 64);
    #pragma unroll
    for (int bf = 0; bf < 4; ++bf) {
      short8 bv = *(const short8*)(col + (long)(n0 + bf * 16 + ln) * 64 + kc * 32 + quad * 8);
      acc[0][bf] = __builtin_amdgcn_mfma_f32_16x16x32_bf16(a0, bv, acc[0][bf], 0, 0, 0);
      acc[1][bf] = __builtin_amdgcn_mfma_f32_16x16x32_bf16(a1, bv, acc[1][bf], 0, 0, 0);
    }
  }
  #pragma unroll
  for (int mf = 0; mf < 2; ++mf) {
    int coB = wm * 32 + mf * 16 + quad * 4;
    float4v bv4 = *(const float4v*)(bias + coB);
    #pragma unroll
    for (int bf = 0; bf < 4; ++bf) {
      int n = n0 + bf * 16 + ln;
      int ow = n & 127; int t2 = n >> 7;
      int oh = t2 & 127; int b = t2 >> 7;
      long oaddr = ((long)(b * 130 + oh + 1) * 130 + ow + 1) * 64 + coB;
      float4v v = acc[mf][bf];
      ushort4v o;
      #pragma unroll
      for (int e = 0; e < 4; ++e) o[e] = f2bfbits(fmaxf(v[e] + bv4[e], 0.f));
      *(ushort4v*)(act1p + oaddr) = o;
    }
  }
}

// ------------------------------------------- MFMA implicit-GEMM tap conv
// Weights in fragment order (frag_pack). NBF = B-frags per wave.
template <int COUT, int CINT, int TC, int S, int NT, int INC, int NBF>
__global__ __launch_bounds__(256) void mfma_conv(
    const bf16* __restrict__ in1, const bf16* __restrict__ in2,
    long inImgS, int inRowS,
    const bf16* __restrict__ wf, const float* __restrict__ bias,
    bf16* __restrict__ outp, long outImgS, int oRS, int oCS,
    int nxb, long po, long qo) {
  constexpr int TR = (2 * NBF * 16) / TC;
  constexpr int KC = CINT / 32;
  constexpr int MC = COUT / 32;
  constexpr int KSPLIT = (CINT > INC) ? (INC / 32) : KC;
  const int lane = threadIdx.x & 63;
  const int wv = threadIdx.x >> 6;
  const int wm = wv & 1, wn = wv >> 1;
  const int ln = lane & 15, quad = lane >> 4;
  const int cls = blockIdx.x >> nxb;
  const int xb = blockIdx.x & ((1u << nxb) - 1u);
  const int mTile = blockIdx.y * 64;
  const int mc = blockIdx.y * 2 + wm;
  const int oh0 = xb * TR;
  const int b = blockIdx.z;
  const int p = cls >> 1, q = cls & 1;
  const long ooff = (long)(p + 1) * po + (long)(q + 1) * qo;

  long posOff[NBF];
  int rr[NBF], cc[NBF];
  #pragma unroll
  for (int bf = 0; bf < NBF; ++bf) {
    int n = wn * (NBF * 16) + bf * 16 + ln;
    int r = n / TC, c = n % TC;
    rr[bf] = r; cc[bf] = c;
    posOff[bf] = (long)(S * (oh0 + r)) * inRowS + (long)(S * c) * INC;
  }
  const bf16* inb1 = in1 + (long)b * inImgS;
  const bf16* inb2 = in2 + (long)b * inImgS;

  float4v acc[2][NBF];
  #pragma unroll
  for (int i = 0; i < 2; ++i)
    #pragma unroll
    for (int j = 0; j < NBF; ++j) acc[i][j] = {0.f, 0.f, 0.f, 0.f};

  for (int t = 0; t < NT; ++t) {
    int dy, dx;
    if (S == 2) { dy = t >> 2; dx = t & 3; }
    else        { dy = p - (t >> 1) + 1; dx = q - (t & 1) + 1; }
    const long tapOff = (long)dy * inRowS + (long)dx * INC;
    const bf16* wt = wf + ((long)(cls * NT + t) * MC + mc) * (KC * 1024) + ln * 32 + quad * 8;
    #pragma unroll
    for (int kc = 0; kc < KC; ++kc) {
      short8 a0 = *(const short8*)(wt + kc * 1024);
      short8 a1 = *(const short8*)(wt + kc * 1024 + 512);
      const bf16* bp = (kc < KSPLIT) ? inb1 : inb2;
      int kOff = (kc < KSPLIT ? kc : kc - KSPLIT) * 32 + quad * 8;
      #pragma unroll
      for (int bf = 0; bf < NBF; ++bf) {
        short8 bv = *(const short8*)(bp + posOff[bf] + tapOff + kOff);
        acc[0][bf] = __builtin_amdgcn_mfma_f32_16x16x32_bf16(a0, bv, acc[0][bf], 0, 0, 0);
        acc[1][bf] = __builtin_amdgcn_mfma_f32_16x16x32_bf16(a1, bv, acc[1][bf], 0, 0, 0);
      }
    }
  }

  bf16* outb = outp + (long)b * outImgS + ooff;
  #pragma unroll
  for (int mf = 0; mf < 2; ++mf) {
    int coB = mTile + wm * 32 + mf * 16 + quad * 4;
    float4v bv4 = *(const float4v*)(bias + coB);
    #pragma unroll
    for (int bf = 0; bf < NBF; ++bf) {
      float4v v = acc[mf][bf];
      ushort4v o;
      #pragma unroll
      for (int e = 0; e < 4; ++e)
        o[e] = f2bfbits(fmaxf(v[e] + bv4[e], 0.f));
      long oaddr = (long)(oh0 + rr[bf]) * oRS + (long)cc[bf] * oCS + coB;
      *(ushort4v*)(outb + oaddr) = o;
    }
  }
}

// ------------- d1 (concat 256 -> 64) wave M64xN64: 16 MFMA per 8 loads
__global__ __launch_bounds__(256) void mfma_d1(
    const bf16* __restrict__ in1, const bf16* __restrict__ in2,
    const bf16* __restrict__ wf, const float* __restrict__ bias,
    bf16* __restrict__ outp) {
  const int lane = threadIdx.x & 63, wv = threadIdx.x >> 6;
  const int ln = lane & 15, quad = lane >> 4;
  const int cls = blockIdx.x >> 4;
  const int xb = blockIdx.x & 15;
  const int b = blockIdx.z;
  const int p = cls >> 1, q = cls & 1;
  const int row = xb * 4 + wv;             // class-row in [0,64)
  const bf16* inb1 = in1 + (long)b * 557568;
  const bf16* inb2 = in2 + (long)b * 557568;
  const long rowOff = (long)row * 8448;
  long colOff[4];
  #pragma unroll
  for (int bf = 0; bf < 4; ++bf) colOff[bf] = (long)(bf * 16 + ln) * 128 + quad * 8;

  float4v acc[4][4];
  #pragma unroll
  for (int j = 0; j < 4; ++j)
    #pragma unroll
    for (int bf = 0; bf < 4; ++bf) acc[j][bf] = {0.f, 0.f, 0.f, 0.f};

  #pragma unroll
  for (int t = 0; t < 4; ++t) {
    int dy = p - (t >> 1) + 1, dx = q - (t & 1) + 1;
    long tapOff = rowOff + (long)dy * 8448 + (long)dx * 128;
    const bf16* wt = wf + (long)(cls * 4 + t) * 16384 + ln * 32 + quad * 8;
    #pragma unroll
    for (int kc = 0; kc < 8; ++kc) {
      const bf16* wk = wt + kc * 2048;
      short8 a0 = *(const short8*)(wk);
      short8 a1 = *(const short8*)(wk + 512);
      short8 a2 = *(const short8*)(wk + 1024);
      short8 a3 = *(const short8*)(wk + 1536);
      const bf16* bp = ((kc < 4) ? inb1 : inb2) + tapOff + (kc & 3) * 32;
      #pragma unroll
      for (int bf = 0; bf < 4; ++bf) {
        short8 bv = *(const short8*)(bp + colOff[bf]);
        acc[0][bf] = __builtin_amdgcn_mfma_f32_16x16x32_bf16(a0, bv, acc[0][bf], 0, 0, 0);
        acc[1][bf] = __builtin_amdgcn_mfma_f32_16x16x32_bf16(a1, bv, acc[1][bf], 0, 0, 0);
        acc[2][bf] = __builtin_amdgcn_mfma_f32_16x16x32_bf16(a2, bv, acc[2][bf], 0, 0, 0);
        acc[3][bf] = __builtin_amdgcn_mfma_f32_16x16x32_bf16(a3, bv, acc[3][bf], 0, 0, 0);
      }
    }
  }

  bf16* outb = outp + (long)b * 1081600 + (long)(p + 1) * 8320 + (long)(q + 1) * 64 +
               (long)row * 16640;
  #pragma unroll
  for (int j = 0; j < 4; ++j) {
    int co = j * 16 + quad * 4;
    float4v bv4 = *(const float4v*)(bias + co);
    #pragma unroll
    for (int bf = 0; bf < 4; ++bf) {
      float4v v = acc[j][bf];
      ushort4v o;
      #pragma unroll
      for (int e = 0; e < 4; ++e)
        o[e] = f2bfbits(fmaxf(v[e] + bv4[e], 0.f));
      *(ushort4v*)(outb + (long)(bf * 16 + ln) * 128 + co) = o;
    }
  }
}

// ---------------------------------------------------- VQ via MFMA GEMM
__global__ __launch_bounds__(256) void vq_mfma(
    const bf16* __restrict__ z, long zImgS, int zRowS,
    const bf16* __restrict__ emb, const float* __restrict__ embsq,
    bf16* __restrict__ zq, long qImgS, int qRowS,
    float* __restrict__ loss_acc, int wb, int hwb) {
  const int lane = threadIdx.x & 63, wv = threadIdx.x >> 6;
  const int ln = lane & 15, quad = lane >> 4;
  const int base = blockIdx.x * 256 + wv * 64;

  short8 bfrag[4][4];
  #pragma unroll
  for (int bf = 0; bf < 4; ++bf) {
    int n = base + bf * 16 + ln;
    int b = n >> hwb;
    int rem = n & ((1 << hwb) - 1);
    int y = rem >> wb, x = rem & ((1 << wb) - 1);
    const bf16* zrow = z + (long)b * zImgS + (long)y * zRowS + (long)x * 128;
    #pragma unroll
    for (int kc = 0; kc < 4; ++kc)
      bfrag[bf][kc] = *(const short8*)(zrow + kc * 32 + quad * 8);
  }

  float best0 = 3.4e38f, best1 = 3.4e38f, best2 = 3.4e38f, best3 = 3.4e38f;
  int bk0 = 0, bk1 = 0, bk2 = 0, bk3 = 0;
  for (int ct = 0; ct < 32; ++ct) {
    const bf16* erow = emb + (long)(ct * 16 + ln) * 128 + quad * 8;
    short8 a0 = *(const short8*)(erow);
    short8 a1 = *(const short8*)(erow + 32);
    short8 a2 = *(const short8*)(erow + 64);
    short8 a3 = *(const short8*)(erow + 96);
    float4v sq4 = *(const float4v*)(embsq + ct * 16 + quad * 4);
    #pragma unroll
    for (int bf = 0; bf < 4; ++bf) {
      float4v acc = {0.f, 0.f, 0.f, 0.f};
      acc = __builtin_amdgcn_mfma_f32_16x16x32_bf16(a0, bfrag[bf][0], acc, 0, 0, 0);
      acc = __builtin_amdgcn_mfma_f32_16x16x32_bf16(a1, bfrag[bf][1], acc, 0, 0, 0);
      acc = __builtin_amdgcn_mfma_f32_16x16x32_bf16(a2, bfrag[bf][2], acc, 0, 0, 0);
      acc = __builtin_amdgcn_mfma_f32_16x16x32_bf16(a3, bfrag[bf][3], acc, 0, 0, 0);
      int kb = ct * 16 + quad * 4;
      #pragma unroll
      for (int r = 0; r < 4; ++r) {
        float s = fmaf(-2.f, acc[r], sq4[r]);
        if (bf == 0) { if (s < best0) { best0 = s; bk0 = kb + r; } }
        if (bf == 1) { if (s < best1) { best1 = s; bk1 = kb + r; } }
        if (bf == 2) { if (s < best2) { best2 = s; bk2 = kb + r; } }
        if (bf == 3) { if (s < best3) { best3 = s; bk3 = kb + r; } }
      }
    }
  }
  float bs[4] = {best0, best1, best2, best3};
  int bk[4] = {bk0, bk1, bk2, bk3};
  #pragma unroll
  for (int bf = 0; bf < 4; ++bf) {
    #pragma unroll
    for (int m = 16; m <= 32; m <<= 1) {
      float os = __shfl_xor(bs[bf], m, 64);
      int ok = __shfl_xor(bk[bf], m, 64);
      if (os < bs[bf] || (os == bs[bf] && ok < bk[bf])) { bs[bf] = os; bk[bf] = ok; }
    }
  }
  int myk = (quad == 0) ? bk[0] : (quad == 1) ? bk[1] : (quad == 2) ? bk[2] : bk[3];
  int n = base + quad * 16 + ln;
  int b = n >> hwb;
  int rem = n & ((1 << hwb) - 1);
  int y = rem >> wb, x = rem & ((1 << wb) - 1);
  const uint4* zr = (const uint4*)(z + (long)b * zImgS + (long)y * zRowS + (long)x * 128);
  uint4* qr = (uint4*)(zq + (long)b * qImgS + (long)y * qRowS + (long)x * 128);
  const uint4* er = (const uint4*)(emb + (long)myk * 128);
  float lsum = 0.f;
  #pragma unroll
  for (int j = 0; j < 16; ++j) {
    uint4 ue = er[j];
    uint4 uz = zr[j];
    qr[j] = ue;
    float ev[8], zv[8];
    unpack_u4(ue, ev);
    unpack_u4(uz, zv);
    #pragma unroll
    for (int e = 0; e < 8; ++e) {
      float dv = ev[e] - zv[e];
      lsum = fmaf(dv, dv, lsum);
    }
  }
  for (int o = 32; o > 0; o >>= 1) lsum += __shfl_down(lsum, o, 64);
  if (lane == 0) atomicAdd(loss_acc, lsum);
}

// --------------------- final convT(64->3)+sigmoid via class-packed MFMA
__global__ __launch_bounds__(256) void final_convt_mfma(
    const bf16* __restrict__ hp, const bf16* __restrict__ wfin,
    const float* __restrict__ bf_, float* __restrict__ out) {
  const int lane = threadIdx.x & 63, wv = threadIdx.x >> 6;
  const int ln = lane & 15, quad = lane >> 4;
  const int base = blockIdx.x * 256 + wv * 64;   // 262144 positions total

  short8 afr[18];
  #pragma unroll
  for (int kc = 0; kc < 18; ++kc)
    afr[kc] = *(const short8*)(wfin + ln * 576 + kc * 32 + quad * 8);

  float4v acc[4];
  #pragma unroll
  for (int bf = 0; bf < 4; ++bf) acc[bf] = {0.f, 0.f, 0.f, 0.f};

  #pragma unroll
  for (int bf = 0; bf < 4; ++bf) {
    int n = base + bf * 16 + ln;
    int xx = n & 127, y = (n >> 7) & 127, b = n >> 14;
    const bf16* hb = hp + (long)b * 1081600 + (long)y * 8320 + (long)xx * 64;
    #pragma unroll
    for (int kc = 0; kc < 18; ++kc) {
      int d = kc >> 1;
      const bf16* bp = hb + (long)(d / 3) * 8320 + (d % 3) * 64 + (kc & 1) * 32 + quad * 8;
      short8 bv = *(const short8*)bp;
      acc[bf] = __builtin_amdgcn_mfma_f32_16x16x32_bf16(afr[kc], bv, acc[bf], 0, 0, 0);
    }
  }

  const int p = quad >> 1, q = quad & 1;
  float b0 = bf_[0], b1 = bf_[1], b2 = bf_[2];
  #pragma unroll
  for (int bf = 0; bf < 4; ++bf) {
    int n = base + bf * 16 + ln;
    int xx = n & 127, y = (n >> 7) & 127, b = n >> 14;
    long ob = (long)b * 196608 + (long)(2 * y + p) * 256 + (2 * xx + q);
    float v0 = acc[bf][0] + b0, v1 = acc[bf][1] + b1, v2 = acc[bf][2] + b2;
    out[ob]          = 1.f / (1.f + expf(-v0));
    out[ob + 65536]  = 1.f / (1.f + expf(-v1));
    out[ob + 131072] = 1.f / (1.f + expf(-v2));
  }
}

__global__ void finalize_loss_kernel(const float* __restrict__ lacc, float* __restrict__ out) {
  if (threadIdx.x == 0) {
    float lt = lacc[0] * (1.5f / 2097152.f);
    float lb = lacc[1] * (1.5f / 8388608.f);
    *out = lt + lb;
  }
}

// ------------------------------------------------------------------ launch
extern "C" void kernel_launch(void* const* d_in, const int* in_sizes, int n_in,
                              void* d_out, int out_size, void* d_ws, size_t ws_size,
                              hipStream_t stream) {
  float* out = (float*)d_out;
  char* base = (char*)d_ws;
  size_t off = 0;
  auto alloc = [&](size_t bytes) {
    void* pp = base + off;
    off = (off + bytes + 255) & ~(size_t)255;
    return pp;
  };

  int* flag = (int*)alloc(256);
  float* biasAll = (float*)alloc(515 * 4);
  float* beB1f = biasAll + 0;
  float* beB2f = biasAll + 64;
  float* beTf  = biasAll + 192;
  float* bdTf  = biasAll + 320;
  float* bd1f  = biasAll + 448;
  float* bd2f  = biasAll + 512;
  float* sqAll = (float*)alloc(1024 * 4);
  float* sqT = sqAll, *sqB = sqAll + 512;
  float* lacc = (float*)alloc(2 * 4);
  bf16* Wc1  = (bf16*)alloc((size_t)4096 * 2);
  bf16* Wt2  = (bf16*)alloc((size_t)131072 * 2);
  bf16* Wtt  = (bf16*)alloc((size_t)262144 * 2);
  bf16* Wdt  = (bf16*)alloc((size_t)262144 * 2);
  bf16* Wt2f = (bf16*)alloc((size_t)131072 * 2);
  bf16* Wttf = (bf16*)alloc((size_t)262144 * 2);
  bf16* Wdtf = (bf16*)alloc((size_t)262144 * 2);
  bf16* Wd1f = (bf16*)alloc((size_t)262144 * 2);
  bf16* Wfin = (bf16*)alloc((size_t)9216 * 2);
  bf16* embTB = (bf16*)alloc((size_t)131072 * 2);
  bf16* embT = embTB, *embB = embTB + 65536;
  bf16* colb = (bf16*)alloc((size_t)16777216 * 2);   // im2col [262144][64]
  bf16* act1p = (bf16*)alloc((size_t)17305600 * 2);  // [16][130][130][64]
  bf16* zbp   = (bf16*)alloc((size_t)8921088 * 2);   // [16][66][66][128]
  bf16* zqtp  = (bf16*)alloc((size_t)2367488 * 2);   // [16][34][34][128]
  bf16* eup   = (bf16*)alloc((size_t)8921088 * 2);   // [16][66][66][128]
  bf16* fqp   = (bf16*)alloc((size_t)8921088 * 2);   // [16][66][66][128]
  bf16* hp    = (bf16*)alloc((size_t)17305600 * 2);  // [16][130][130][64]
  bf16* ztp   = (bf16*)alloc((size_t)2097152 * 2);   // [16][32][32][128]

  detect_dtype_kernel<<<1, 256, 0, stream>>>(d_in[0], flag);
  zero2_kernel<<<1, 64, 0, stream>>>(lacc);

  // halo-only zeroing (interiors are fully overwritten by their producers)
  zero_halo<<<517, 256, 0, stream>>>(act1p, hp, nullptr, 2, 130, 130, 8, 1081600, 16, 4128);
  zero_halo<<<781, 256, 0, stream>>>(zbp, eup, fqp, 3, 66, 66, 16, 557568, 16, 4160);
  zero_halo<<<132, 256, 0, stream>>>(zqtp, nullptr, nullptr, 1, 34, 34, 16, 147968, 16, 2112);

  // converts / repacks
  conv_bias_all<<<3, 256, 0, stream>>>(d_in[2], d_in[4], d_in[6], d_in[10],
                                       d_in[12], d_in[14], biasAll, flag);
  conv_emb<<<512, 256, 0, stream>>>(d_in[7], d_in[8], embTB, flag);
  embsq2<<<4, 256, 0, stream>>>(embTB, sqAll);
  rp_c1w<<<16, 256, 0, stream>>>(d_in[1], Wc1, flag);
  rp_conv_w<128, 64><<<512, 256, 0, stream>>>(d_in[3], Wt2, flag);
  rp_conv_w<128, 128><<<1024, 256, 0, stream>>>(d_in[5], Wtt, flag);
  rp_convt_w<128, 128><<<1024, 256, 0, stream>>>(d_in[9], Wdt, flag);
  rp_d1f<<<1024, 256, 0, stream>>>(d_in[11], Wd1f, flag);
  rp_finw<<<36, 256, 0, stream>>>(d_in[13], Wfin, flag);
  frag_pack<4, 2><<<512, 256, 0, stream>>>(Wt2, Wt2f, 131072);
  frag_pack<4, 4><<<1024, 256, 0, stream>>>(Wtt, Wttf, 262144);
  frag_pack<4, 4><<<1024, 256, 0, stream>>>(Wdt, Wdtf, 262144);

  // encoder: conv1 = im2col + MFMA GEMM
  im2col1<<<1024, 256, 0, stream>>>(d_in[0], flag, colb);
  gemm1<<<2048, 256, 0, stream>>>(colb, Wc1, beB1f, act1p);
  // conv2: NBF=2, TR=1 -> 2048 blocks
  mfma_conv<128, 64, 64, 2, 16, 64, 2><<<dim3(64, 2, 16), 256, 0, stream>>>(
      act1p, act1p, 1081600, 8320, Wt2f, beB2f, zbp + 8576, 557568, 8448, 128, 30, 0, 0);
  // conv_t: NBF=2, TR=2 -> 512 blocks
  mfma_conv<128, 128, 32, 2, 16, 128, 2><<<dim3(16, 2, 16), 256, 0, stream>>>(
      zbp, zbp, 557568, 8448, Wttf, beTf, ztp, 131072, 4096, 128, 30, 0, 0);

  // VQ top (16384 positions)
  vq_mfma<<<64, 256, 0, stream>>>(ztp, 131072, 4096, embT, sqT,
                                  zqtp + 4480, 147968, 4352, lacc + 0, 5, 10);

  // decoder_top upsample: 4 classes in one launch (nxb=4: 16 x-blocks/class)
  mfma_conv<128, 128, 32, 1, 4, 128, 2><<<dim3(64, 2, 16), 256, 0, stream>>>(
      zqtp, zqtp, 147968, 4352, Wdtf, bdTf, eup, 557568, 16896, 256, 4, 8448, 128);

  // VQ bottom (65536 positions)
  vq_mfma<<<256, 256, 0, stream>>>(zbp + 8576, 557568, 8448, embB, sqB,
                                   fqp + 8576, 557568, 8448, lacc + 1, 6, 12);

  // decoder conv d1: wave M64xN64, 1024 blocks
  mfma_d1<<<dim3(64, 1, 16), 256, 0, stream>>>(fqp, eup, Wd1f, bd1f, hp);

  // final convT + sigmoid via MFMA -> fp32 NCHW output
  final_convt_mfma<<<1024, 256, 0, stream>>>(hp, Wfin, bd2f, out);
  finalize_loss_kernel<<<1, 64, 0, stream>>>(lacc, out + 3145728);
}

// Round 12
// 553.537 us; speedup vs baseline: 1.3941x; 1.0809x over previous
//
#include <hip/hip_runtime.h>
#include <hip/hip_bf16.h>
#include <cstddef>

typedef __hip_bfloat16 bf16;
typedef __attribute__((ext_vector_type(8))) short short8;
typedef __attribute__((ext_vector_type(4))) float float4v;
typedef __attribute__((ext_vector_type(4))) unsigned short ushort4v;

static __device__ __forceinline__ float b2f(bf16 v) { return __bfloat162float(v); }
static __device__ __forceinline__ float bits2f(unsigned int u) { return __uint_as_float(u); }
static __device__ __forceinline__ unsigned short f2bfbits(float f) {
  bf16 h = __float2bfloat16(f);
  return *reinterpret_cast<unsigned short*>(&h);
}
static __device__ __forceinline__ float ld_any(const void* p, long i, int flag) {
  return flag ? b2f(((const bf16*)p)[i]) : ((const float*)p)[i];
}
static __device__ __forceinline__ void unpack_u4(uint4 u, float* f) {
  f[0] = bits2f(u.x << 16); f[1] = bits2f(u.x & 0xffff0000u);
  f[2] = bits2f(u.y << 16); f[3] = bits2f(u.y & 0xffff0000u);
  f[4] = bits2f(u.z << 16); f[5] = bits2f(u.z & 0xffff0000u);
  f[6] = bits2f(u.w << 16); f[7] = bits2f(u.w & 0xffff0000u);
}

// --------------------------------------------------------- dtype detection
__global__ void detect_dtype_kernel(const void* __restrict__ x, int* __restrict__ flag) {
  __shared__ int ok;
  if (threadIdx.x == 0) ok = 1;
  __syncthreads();
  float v = b2f(((const bf16*)x)[threadIdx.x]);
  if (!(v >= 0.f && v <= 1.0009765625f)) ok = 0;
  __syncthreads();
  if (threadIdx.x == 0) *flag = ok;
}

// ---------------------------------------------------------------- utilities
__global__ void zero2_kernel(float* p) {
  if (threadIdx.x < 2) p[threadIdx.x] = 0.f;
}

// zero only the 1-wide halo ring of up to 3 same-shape padded NHWC buffers
__global__ void zero_halo(bf16* p0, bf16* p1, bf16* p2, int np,
                          int H, int W, int C8, long imgS, int nimg, int gpi) {
  int tid = blockIdx.x * 256 + threadIdx.x;
  int total = nimg * gpi;
  int which = tid / total;
  if (which >= np) return;
  int r = tid - which * total;
  int img = r / gpi, g = r % gpi;
  int pos = g / C8, c8 = g % C8;
  int row, col;
  if (pos < W) { row = 0; col = pos; }
  else if (pos < 2 * W) { row = H - 1; col = pos - W; }
  else { int s = pos - 2 * W; row = 1 + (s >> 1); col = (s & 1) ? (W - 1) : 0; }
  bf16* base = (which == 0) ? p0 : ((which == 1) ? p1 : p2);
  uint4* dst = (uint4*)(base + (long)img * imgS + ((long)row * W + col) * (C8 * 8) + (long)c8 * 8);
  *dst = uint4{0u, 0u, 0u, 0u};
}

// all 6 conv biases -> one fp32 buffer
__global__ void conv_bias_all(const void* s2, const void* s4, const void* s6,
                              const void* s10, const void* s12, const void* s14,
                              float* __restrict__ dst, const int* __restrict__ flag) {
  int i = blockIdx.x * 256 + threadIdx.x;
  if (i >= 515) return;
  int fl = *flag;
  const void* s; int off;
  if (i < 64)       { s = s2;  off = i; }
  else if (i < 192) { s = s4;  off = i - 64; }
  else if (i < 320) { s = s6;  off = i - 192; }
  else if (i < 448) { s = s10; off = i - 320; }
  else if (i < 512) { s = s12; off = i - 448; }
  else              { s = s14; off = i - 512; }
  dst[i] = ld_any(s, off, fl);
}

// both codebooks -> contiguous bf16 [1024][128]
__global__ void conv_emb(const void* __restrict__ sT, const void* __restrict__ sB,
                         bf16* __restrict__ dst, const int* __restrict__ flag) {
  int i = blockIdx.x * 256 + threadIdx.x;   // 131072
  int fl = *flag;
  const void* s = (i < 65536) ? sT : sB;
  int off = i & 65535;
  dst[i] = fl ? ((const bf16*)s)[off] : __float2bfloat16(((const float*)s)[off]);
}

__global__ void embsq2(const bf16* __restrict__ embTB, float* __restrict__ sqAll) {
  int k = blockIdx.x * blockDim.x + threadIdx.x;
  if (k >= 1024) return;
  float s = 0.f;
  const bf16* e = embTB + (long)k * 128;
  for (int c = 0; c < 128; ++c) { float v = b2f(e[c]); s = fmaf(v, v, s); }
  sqAll[k] = s;
}

// conv1 weights [64][3][4][4] -> [co][k] bf16, K padded 48->64 with zeros
__global__ void rp_c1w(const void* __restrict__ src, bf16* __restrict__ dst,
                       const int* __restrict__ flag) {
  int i = blockIdx.x * blockDim.x + threadIdx.x;   // 64*64
  if (i >= 4096) return;
  int co = i >> 6, k = i & 63;
  float v = (k < 48) ? ld_any(src, co * 48 + k, *flag) : 0.f;
  dst[i] = __float2bfloat16(v);
}

// weights OIHW [CO][CI][4][4] -> [tap=kh*4+kw][co][ci] bf16
template <int CO, int CI>
__global__ void rp_conv_w(const void* __restrict__ src, bf16* __restrict__ dst,
                          const int* __restrict__ flag) {
  const int N = CO * CI * 16;
  int i = blockIdx.x * blockDim.x + threadIdx.x;
  if (i >= N) return;
  int co = i / (CI * 16);
  int rem = i % (CI * 16);
  int ci = rem >> 4;
  int k = rem & 15;
  dst[((long)k * CO + co) * CI + ci] = __float2bfloat16(ld_any(src, i, *flag));
}

// convT weights [CI][CO][4][4] -> [class pq][tap st][co][ci] bf16
template <int CI, int CO>
__global__ void rp_convt_w(const void* __restrict__ src, bf16* __restrict__ dst,
                           const int* __restrict__ flag) {
  const int N = CI * CO * 16;
  int i = blockIdx.x * blockDim.x + threadIdx.x;
  if (i >= N) return;
  int ci = i / (CO * 16);
  int rem = i % (CO * 16);
  int co = rem >> 4;
  int k = rem & 15;
  int kh = k >> 2, kw = k & 3;
  int p = (kh + 1) & 1, s = (kh - 1 + p) >> 1;
  int q = (kw + 1) & 1, t = (kw - 1 + q) >> 1;
  long d = (((long)(p * 2 + q) * 4 + (s * 2 + t)) * CO + co) * CI + ci;
  dst[d] = __float2bfloat16(ld_any(src, i, *flag));
}

// [tg][co][ci] -> fragment order [((tg*MC+mc)*KC+kc)*2+j][ln][quad*8]
template <int MC, int KC>
__global__ void frag_pack(const bf16* __restrict__ src, bf16* __restrict__ dst, int total) {
  int i = blockIdx.x * 256 + threadIdx.x;
  if (i >= total) return;
  int low = i & 511;
  int ln = low >> 5, cl = low & 31;
  int c2 = i >> 9;
  int j = c2 & 1;
  int c3 = c2 >> 1;
  int kc = c3 & (KC - 1);
  int c4 = c3 / KC;
  int mc = c4 & (MC - 1);
  int tg = c4 / MC;
  int co = mc * 32 + j * 16 + ln;
  int ci = kc * 32 + cl;
  dst[i] = src[((long)tg * (MC * 32) + co) * (KC * 32) + ci];
}

// d1 weights [256ci][64co][4][4] -> frag [(((cls*4+t)*8+kc)*4+j)][ln][quad*8]
__global__ void rp_d1f(const void* __restrict__ src, bf16* __restrict__ dst,
                       const int* __restrict__ flag) {
  int i = blockIdx.x * 256 + threadIdx.x;   // 262144
  if (i >= 262144) return;
  int low = i & 511;
  int ln = low >> 5, cl = low & 31;
  int c2 = i >> 9;
  int j = c2 & 3;
  int kc = (c2 >> 2) & 7;
  int t = (c2 >> 5) & 3;
  int cls = c2 >> 7;
  int p = cls >> 1, q = cls & 1;
  int s = t >> 1, t2 = t & 1;
  int kh = 2 * s + 1 - p, kw = 2 * t2 + 1 - q;
  int co = j * 16 + ln, ci = kc * 32 + cl;
  dst[i] = __float2bfloat16(ld_any(src, (long)ci * 1024 + co * 16 + kh * 4 + kw, *flag));
}

// final convT weights [64ci][3co][4][4] -> A[m=cls*4+co][d=dy*3+dx][64ci]
__global__ void rp_finw(const void* __restrict__ src, bf16* __restrict__ dst,
                        const int* __restrict__ flag) {
  int i = blockIdx.x * blockDim.x + threadIdx.x;   // 16*576 = 9216
  if (i >= 9216) return;
  int m = i / 576, rem = i % 576;
  int d = rem >> 6, ci = rem & 63;
  int cls = m >> 2, co = m & 3;
  int p = cls >> 1, q = cls & 1;
  int dy = d / 3, dx = d % 3;
  int s = p - dy + 1, t = q - dx + 1;
  float v = 0.f;
  if (co < 3 && s >= 0 && s <= 1 && t >= 0 && t <= 1) {
    int kh = 2 * s + 1 - p, kw = 2 * t + 1 - q;
    v = ld_any(src, ci * 48 + co * 16 + kh * 4 + kw, *flag);
  }
  dst[i] = __float2bfloat16(v);
}

// -------------------- conv1 as GEMM: im2col (K padded to 64) + MFMA GEMM
__global__ __launch_bounds__(256) void im2col1(const void* __restrict__ x,
                                               const int* __restrict__ flag,
                                               bf16* __restrict__ col) {
  int tid = blockIdx.x * 256 + threadIdx.x;   // 16*128*128
  int ow = tid & 127; int t = tid >> 7;
  int oh = t & 127; int b = t >> 7;
  int fl = *flag;
  int ih0 = oh * 2 - 1, iw0 = ow * 2 - 1;
  unsigned short vals[64];
  #pragma unroll
  for (int j = 48; j < 64; ++j) vals[j] = 0;
  #pragma unroll
  for (int ci = 0; ci < 3; ++ci) {
    long pbase = ((long)(b * 3 + ci)) << 16;
    #pragma unroll
    for (int kh = 0; kh < 4; ++kh) {
      int ih = ih0 + kh;
      bool okh = (unsigned)ih < 256u;
      long rbase = pbase + ((long)ih << 8);
      #pragma unroll
      for (int kw = 0; kw < 4; ++kw) {
        int iw = iw0 + kw;
        float v = (okh && (unsigned)iw < 256u) ? ld_any(x, rbase + iw, fl) : 0.f;
        vals[ci * 16 + kh * 4 + kw] = f2bfbits(v);
      }
    }
  }
  uint4* dst = (uint4*)(col + (long)tid * 64);
  const uint4* s = (const uint4*)vals;
  #pragma unroll
  for (int j = 0; j < 8; ++j) dst[j] = s[j];
}

// M=64 (co), K=64, N=262144 (positions); bias+relu; store padded NHWC
__global__ __launch_bounds__(256) void gemm1(const bf16* __restrict__ col,
                                             const bf16* __restrict__ w,
                                             const float* __restrict__ bias,
                                             bf16* __restrict__ act1p) {
  const int lane = threadIdx.x & 63, wv = threadIdx.x >> 6;
  const int wm = wv & 1, wn = wv >> 1;
  const int ln = lane & 15, quad = lane >> 4;
  const int n0 = blockIdx.x * 128 + wn * 64;
  float4v acc[2][4];
  #pragma unroll
  for (int i = 0; i < 2; ++i)
    #pragma unroll
    for (int j = 0; j < 4; ++j) acc[i][j] = {0.f, 0.f, 0.f, 0.f};
  #pragma unroll
  for (int kc = 0; kc < 2; ++kc) {
    const bf16* wk = w + (wm * 32 + ln) * 64 + kc * 32 + quad * 8;
    short8 a0 = *(const short8*)(wk);
    short8 a1 = *(const short8*)(wk + 16 * 64);
    #pragma unroll
    for (int bf = 0; bf < 4; ++bf) {
      short8 bv = *(const short8*)(col + (long)(n0 + bf * 16 + ln) * 64 + kc * 32 + quad * 8);
      acc[0][bf] = __builtin_amdgcn_mfma_f32_16x16x32_bf16(a0, bv, acc[0][bf], 0, 0, 0);
      acc[1][bf] = __builtin_amdgcn_mfma_f32_16x16x32_bf16(a1, bv, acc[1][bf], 0, 0, 0);
    }
  }
  #pragma unroll
  for (int mf = 0; mf < 2; ++mf) {
    int coB = wm * 32 + mf * 16 + quad * 4;
    float4v bv4 = *(const float4v*)(bias + coB);
    #pragma unroll
    for (int bf = 0; bf < 4; ++bf) {
      int n = n0 + bf * 16 + ln;
      int ow = n & 127; int t2 = n >> 7;
      int oh = t2 & 127; int b = t2 >> 7;
      long oaddr = ((long)(b * 130 + oh + 1) * 130 + ow + 1) * 64 + coB;
      float4v v = acc[mf][bf];
      ushort4v o;
      #pragma unroll
      for (int e = 0; e < 4; ++e) o[e] = f2bfbits(fmaxf(v[e] + bv4[e], 0.f));
      *(ushort4v*)(act1p + oaddr) = o;
    }
  }
}

// ------------------------------------------- MFMA implicit-GEMM tap conv
// Weights in fragment order (frag_pack). NBF = B-frags per wave.
template <int COUT, int CINT, int TC, int S, int NT, int INC, int NBF>
__global__ __launch_bounds__(256) void mfma_conv(
    const bf16* __restrict__ in1, const bf16* __restrict__ in2,
    long inImgS, int inRowS,
    const bf16* __restrict__ wf, const float* __restrict__ bias,
    bf16* __restrict__ outp, long outImgS, int oRS, int oCS,
    int nxb, long po, long qo) {
  constexpr int TR = (2 * NBF * 16) / TC;
  constexpr int KC = CINT / 32;
  constexpr int MC = COUT / 32;
  constexpr int KSPLIT = (CINT > INC) ? (INC / 32) : KC;
  const int lane = threadIdx.x & 63;
  const int wv = threadIdx.x >> 6;
  const int wm = wv & 1, wn = wv >> 1;
  const int ln = lane & 15, quad = lane >> 4;
  const int cls = blockIdx.x >> nxb;
  const int xb = blockIdx.x & ((1u << nxb) - 1u);
  const int mTile = blockIdx.y * 64;
  const int mc = blockIdx.y * 2 + wm;
  const int oh0 = xb * TR;
  const int b = blockIdx.z;
  const int p = cls >> 1, q = cls & 1;
  const long ooff = (long)(p + 1) * po + (long)(q + 1) * qo;

  long posOff[NBF];
  int rr[NBF], cc[NBF];
  #pragma unroll
  for (int bf = 0; bf < NBF; ++bf) {
    int n = wn * (NBF * 16) + bf * 16 + ln;
    int r = n / TC, c = n % TC;
    rr[bf] = r; cc[bf] = c;
    posOff[bf] = (long)(S * (oh0 + r)) * inRowS + (long)(S * c) * INC;
  }
  const bf16* inb1 = in1 + (long)b * inImgS;
  const bf16* inb2 = in2 + (long)b * inImgS;

  float4v acc[2][NBF];
  #pragma unroll
  for (int i = 0; i < 2; ++i)
    #pragma unroll
    for (int j = 0; j < NBF; ++j) acc[i][j] = {0.f, 0.f, 0.f, 0.f};

  for (int t = 0; t < NT; ++t) {
    int dy, dx;
    if (S == 2) { dy = t >> 2; dx = t & 3; }
    else        { dy = p - (t >> 1) + 1; dx = q - (t & 1) + 1; }
    const long tapOff = (long)dy * inRowS + (long)dx * INC;
    const bf16* wt = wf + ((long)(cls * NT + t) * MC + mc) * (KC * 1024) + ln * 32 + quad * 8;
    #pragma unroll
    for (int kc = 0; kc < KC; ++kc) {
      short8 a0 = *(const short8*)(wt + kc * 1024);
      short8 a1 = *(const short8*)(wt + kc * 1024 + 512);
      const bf16* bp = (kc < KSPLIT) ? inb1 : inb2;
      int kOff = (kc < KSPLIT ? kc : kc - KSPLIT) * 32 + quad * 8;
      #pragma unroll
      for (int bf = 0; bf < NBF; ++bf) {
        short8 bv = *(const short8*)(bp + posOff[bf] + tapOff + kOff);
        acc[0][bf] = __builtin_amdgcn_mfma_f32_16x16x32_bf16(a0, bv, acc[0][bf], 0, 0, 0);
        acc[1][bf] = __builtin_amdgcn_mfma_f32_16x16x32_bf16(a1, bv, acc[1][bf], 0, 0, 0);
      }
    }
  }

  bf16* outb = outp + (long)b * outImgS + ooff;
  #pragma unroll
  for (int mf = 0; mf < 2; ++mf) {
    int coB = mTile + wm * 32 + mf * 16 + quad * 4;
    float4v bv4 = *(const float4v*)(bias + coB);
    #pragma unroll
    for (int bf = 0; bf < NBF; ++bf) {
      float4v v = acc[mf][bf];
      ushort4v o;
      #pragma unroll
      for (int e = 0; e < 4; ++e)
        o[e] = f2bfbits(fmaxf(v[e] + bv4[e], 0.f));
      long oaddr = (long)(oh0 + rr[bf]) * oRS + (long)cc[bf] * oCS + coB;
      *(ushort4v*)(outb + oaddr) = o;
    }
  }
}

// ------ d1 (concat 256 -> 64) with LDS-staged input, 4 classes per block
// Block: 4 waves = 4 parity classes, one output class-row r per image.
// Two K-phases (fqp then eup): stage 3 padded rows (198 pos x 128 ch) into
// LDS as short8 chunks (17 chunks/pos: 16 data + 1 pad). A from global.
// FIX vs R11: stage loop covers all 16 chunks/pos (was 8 -> half the
// channels were uninitialized junk -> inf -> NaN downstream).
__global__ __launch_bounds__(256) void mfma_d1_lds(
    const bf16* __restrict__ in1, const bf16* __restrict__ in2,
    const bf16* __restrict__ wf, const float* __restrict__ bias,
    bf16* __restrict__ outp) {
  __shared__ short8 lds8[198 * 17];   // 53856 B
  const int lane = threadIdx.x & 63, wv = threadIdx.x >> 6;
  const int ln = lane & 15, quad = lane >> 4;
  const int r = blockIdx.x;          // output class-row 0..63
  const int b = blockIdx.z;
  const int cls = wv, p = cls >> 1, q = cls & 1;

  const bf16* src1 = in1 + (long)b * 557568 + (long)r * 8448;  // rows r..r+2
  const bf16* src2 = in2 + (long)b * 557568 + (long)r * 8448;

  float4v acc[4][4];   // [j (co chunk)][bf (position chunk)]
  #pragma unroll
  for (int j = 0; j < 4; ++j)
    #pragma unroll
    for (int bf = 0; bf < 4; ++bf) acc[j][bf] = {0.f, 0.f, 0.f, 0.f};

  #pragma unroll
  for (int phase = 0; phase < 2; ++phase) {
    const bf16* src = phase ? src2 : src1;
    __syncthreads();
    for (int i = threadIdx.x; i < 3168; i += 256) {   // 198 pos x 16 chunks
      int pos = i >> 4, j = i & 15;
      lds8[pos * 17 + j] = *(const short8*)(src + (long)pos * 128 + j * 8);
    }
    __syncthreads();
    #pragma unroll
    for (int t = 0; t < 4; ++t) {
      int dy = p - (t >> 1) + 1, dx = q - (t & 1) + 1;
      const bf16* wt = wf + (long)(cls * 4 + t) * 16384 + (long)(phase * 4) * 2048 +
                       ln * 32 + quad * 8;
      const int lbase = (dy * 66 + dx) * 17 + quad;
      #pragma unroll
      for (int kc = 0; kc < 4; ++kc) {
        const bf16* wk = wt + kc * 2048;
        short8 a0 = *(const short8*)(wk);
        short8 a1 = *(const short8*)(wk + 512);
        short8 a2 = *(const short8*)(wk + 1024);
        short8 a3 = *(const short8*)(wk + 1536);
        #pragma unroll
        for (int bf = 0; bf < 4; ++bf) {
          short8 bv = lds8[lbase + kc * 4 + (bf * 16 + ln) * 17];
          acc[0][bf] = __builtin_amdgcn_mfma_f32_16x16x32_bf16(a0, bv, acc[0][bf], 0, 0, 0);
          acc[1][bf] = __builtin_amdgcn_mfma_f32_16x16x32_bf16(a1, bv, acc[1][bf], 0, 0, 0);
          acc[2][bf] = __builtin_amdgcn_mfma_f32_16x16x32_bf16(a2, bv, acc[2][bf], 0, 0, 0);
          acc[3][bf] = __builtin_amdgcn_mfma_f32_16x16x32_bf16(a3, bv, acc[3][bf], 0, 0, 0);
        }
      }
    }
  }

  bf16* outb = outp + (long)b * 1081600 + (long)(p + 1) * 8320 + (long)(q + 1) * 64 +
               (long)r * 16640;
  #pragma unroll
  for (int j = 0; j < 4; ++j) {
    int co = j * 16 + quad * 4;
    float4v bv4 = *(const float4v*)(bias + co);
    #pragma unroll
    for (int bf = 0; bf < 4; ++bf) {
      float4v v = acc[j][bf];
      ushort4v o;
      #pragma unroll
      for (int e = 0; e < 4; ++e)
        o[e] = f2bfbits(fmaxf(v[e] + bv4[e], 0.f));
      *(ushort4v*)(outb + (long)(bf * 16 + ln) * 128 + co) = o;
    }
  }
}

// ---------------------------------------------------- VQ via MFMA GEMM
__global__ __launch_bounds__(256) void vq_mfma(
    const bf16* __restrict__ z, long zImgS, int zRowS,
    const bf16* __restrict__ emb, const float* __restrict__ embsq,
    bf16* __restrict__ zq, long qImgS, int qRowS,
    float* __restrict__ loss_acc, int wb, int hwb) {
  const int lane = threadIdx.x & 63, wv = threadIdx.x >> 6;
  const int ln = lane & 15, quad = lane >> 4;
  const int base = blockIdx.x * 256 + wv * 64;

  short8 bfrag[4][4];
  #pragma unroll
  for (int bf = 0; bf < 4; ++bf) {
    int n = base + bf * 16 + ln;
    int b = n >> hwb;
    int rem = n & ((1 << hwb) - 1);
    int y = rem >> wb, x = rem & ((1 << wb) - 1);
    const bf16* zrow = z + (long)b * zImgS + (long)y * zRowS + (long)x * 128;
    #pragma unroll
    for (int kc = 0; kc < 4; ++kc)
      bfrag[bf][kc] = *(const short8*)(zrow + kc * 32 + quad * 8);
  }

  float best0 = 3.4e38f, best1 = 3.4e38f, best2 = 3.4e38f, best3 = 3.4e38f;
  int bk0 = 0, bk1 = 0, bk2 = 0, bk3 = 0;
  for (int ct = 0; ct < 32; ++ct) {
    const bf16* erow = emb + (long)(ct * 16 + ln) * 128 + quad * 8;
    short8 a0 = *(const short8*)(erow);
    short8 a1 = *(const short8*)(erow + 32);
    short8 a2 = *(const short8*)(erow + 64);
    short8 a3 = *(const short8*)(erow + 96);
    float4v sq4 = *(const float4v*)(embsq + ct * 16 + quad * 4);
    #pragma unroll
    for (int bf = 0; bf < 4; ++bf) {
      float4v acc = {0.f, 0.f, 0.f, 0.f};
      acc = __builtin_amdgcn_mfma_f32_16x16x32_bf16(a0, bfrag[bf][0], acc, 0, 0, 0);
      acc = __builtin_amdgcn_mfma_f32_16x16x32_bf16(a1, bfrag[bf][1], acc, 0, 0, 0);
      acc = __builtin_amdgcn_mfma_f32_16x16x32_bf16(a2, bfrag[bf][2], acc, 0, 0, 0);
      acc = __builtin_amdgcn_mfma_f32_16x16x32_bf16(a3, bfrag[bf][3], acc, 0, 0, 0);
      int kb = ct * 16 + quad * 4;
      #pragma unroll
      for (int r = 0; r < 4; ++r) {
        float s = fmaf(-2.f, acc[r], sq4[r]);
        if (bf == 0) { if (s < best0) { best0 = s; bk0 = kb + r; } }
        if (bf == 1) { if (s < best1) { best1 = s; bk1 = kb + r; } }
        if (bf == 2) { if (s < best2) { best2 = s; bk2 = kb + r; } }
        if (bf == 3) { if (s < best3) { best3 = s; bk3 = kb + r; } }
      }
    }
  }
  float bs[4] = {best0, best1, best2, best3};
  int bk[4] = {bk0, bk1, bk2, bk3};
  #pragma unroll
  for (int bf = 0; bf < 4; ++bf) {
    #pragma unroll
    for (int m = 16; m <= 32; m <<= 1) {
      float os = __shfl_xor(bs[bf], m, 64);
      int ok = __shfl_xor(bk[bf], m, 64);
      if (os < bs[bf] || (os == bs[bf] && ok < bk[bf])) { bs[bf] = os; bk[bf] = ok; }
    }
  }
  int myk = (quad == 0) ? bk[0] : (quad == 1) ? bk[1] : (quad == 2) ? bk[2] : bk[3];
  int n = base + quad * 16 + ln;
  int b = n >> hwb;
  int rem = n & ((1 << hwb) - 1);
  int y = rem >> wb, x = rem & ((1 << wb) - 1);
  const uint4* zr = (const uint4*)(z + (long)b * zImgS + (long)y * zRowS + (long)x * 128);
  uint4* qr = (uint4*)(zq + (long)b * qImgS + (long)y * qRowS + (long)x * 128);
  const uint4* er = (const uint4*)(emb + (long)myk * 128);
  float lsum = 0.f;
  #pragma unroll
  for (int j = 0; j < 16; ++j) {
    uint4 ue = er[j];
    uint4 uz = zr[j];
    qr[j] = ue;
    float ev[8], zv[8];
    unpack_u4(ue, ev);
    unpack_u4(uz, zv);
    #pragma unroll
    for (int e = 0; e < 8; ++e) {
      float dv = ev[e] - zv[e];
      lsum = fmaf(dv, dv, lsum);
    }
  }
  for (int o = 32; o > 0; o >>= 1) lsum += __shfl_down(lsum, o, 64);
  if (lane == 0) atomicAdd(loss_acc, lsum);
}

// --------------------- final convT(64->3)+sigmoid via class-packed MFMA
__global__ __launch_bounds__(256) void final_convt_mfma(
    const bf16* __restrict__ hp, const bf16* __restrict__ wfin,
    const float* __restrict__ bf_, float* __restrict__ out) {
  const int lane = threadIdx.x & 63, wv = threadIdx.x >> 6;
  const int ln = lane & 15, quad = lane >> 4;
  const int base = blockIdx.x * 256 + wv * 64;   // 262144 positions total

  short8 afr[18];
  #pragma unroll
  for (int kc = 0; kc < 18; ++kc)
    afr[kc] = *(const short8*)(wfin + ln * 576 + kc * 32 + quad * 8);

  float4v acc[4];
  #pragma unroll
  for (int bf = 0; bf < 4; ++bf) acc[bf] = {0.f, 0.f, 0.f, 0.f};

  #pragma unroll
  for (int bf = 0; bf < 4; ++bf) {
    int n = base + bf * 16 + ln;
    int xx = n & 127, y = (n >> 7) & 127, b = n >> 14;
    const bf16* hb = hp + (long)b * 1081600 + (long)y * 8320 + (long)xx * 64;
    #pragma unroll
    for (int kc = 0; kc < 18; ++kc) {
      int d = kc >> 1;
      const bf16* bp = hb + (long)(d / 3) * 8320 + (d % 3) * 64 + (kc & 1) * 32 + quad * 8;
      short8 bv = *(const short8*)bp;
      acc[bf] = __builtin_amdgcn_mfma_f32_16x16x32_bf16(afr[kc], bv, acc[bf], 0, 0, 0);
    }
  }

  const int p = quad >> 1, q = quad & 1;
  float b0 = bf_[0], b1 = bf_[1], b2 = bf_[2];
  #pragma unroll
  for (int bf = 0; bf < 4; ++bf) {
    int n = base + bf * 16 + ln;
    int xx = n & 127, y = (n >> 7) & 127, b = n >> 14;
    long ob = (long)b * 196608 + (long)(2 * y + p) * 256 + (2 * xx + q);
    float v0 = acc[bf][0] + b0, v1 = acc[bf][1] + b1, v2 = acc[bf][2] + b2;
    out[ob]          = 1.f / (1.f + expf(-v0));
    out[ob + 65536]  = 1.f / (1.f + expf(-v1));
    out[ob + 131072] = 1.f / (1.f + expf(-v2));
  }
}

__global__ void finalize_loss_kernel(const float* __restrict__ lacc, float* __restrict__ out) {
  if (threadIdx.x == 0) {
    float lt = lacc[0] * (1.5f / 2097152.f);
    float lb = lacc[1] * (1.5f / 8388608.f);
    *out = lt + lb;
  }
}

// ------------------------------------------------------------------ launch
extern "C" void kernel_launch(void* const* d_in, const int* in_sizes, int n_in,
                              void* d_out, int out_size, void* d_ws, size_t ws_size,
                              hipStream_t stream) {
  float* out = (float*)d_out;
  char* base = (char*)d_ws;
  size_t off = 0;
  auto alloc = [&](size_t bytes) {
    void* pp = base + off;
    off = (off + bytes + 255) & ~(size_t)255;
    return pp;
  };

  int* flag = (int*)alloc(256);
  float* biasAll = (float*)alloc(515 * 4);
  float* beB1f = biasAll + 0;
  float* beB2f = biasAll + 64;
  float* beTf  = biasAll + 192;
  float* bdTf  = biasAll + 320;
  float* bd1f  = biasAll + 448;
  float* bd2f  = biasAll + 512;
  float* sqAll = (float*)alloc(1024 * 4);
  float* sqT = sqAll, *sqB = sqAll + 512;
  float* lacc = (float*)alloc(2 * 4);
  bf16* Wc1  = (bf16*)alloc((size_t)4096 * 2);
  bf16* Wt2  = (bf16*)alloc((size_t)131072 * 2);
  bf16* Wtt  = (bf16*)alloc((size_t)262144 * 2);
  bf16* Wdt  = (bf16*)alloc((size_t)262144 * 2);
  bf16* Wt2f = (bf16*)alloc((size_t)131072 * 2);
  bf16* Wttf = (bf16*)alloc((size_t)262144 * 2);
  bf16* Wdtf = (bf16*)alloc((size_t)262144 * 2);
  bf16* Wd1f = (bf16*)alloc((size_t)262144 * 2);
  bf16* Wfin = (bf16*)alloc((size_t)9216 * 2);
  bf16* embTB = (bf16*)alloc((size_t)131072 * 2);
  bf16* embT = embTB, *embB = embTB + 65536;
  bf16* colb = (bf16*)alloc((size_t)16777216 * 2);   // im2col [262144][64]
  bf16* act1p = (bf16*)alloc((size_t)17305600 * 2);  // [16][130][130][64]
  bf16* zbp   = (bf16*)alloc((size_t)8921088 * 2);   // [16][66][66][128]
  bf16* zqtp  = (bf16*)alloc((size_t)2367488 * 2);   // [16][34][34][128]
  bf16* eup   = (bf16*)alloc((size_t)8921088 * 2);   // [16][66][66][128]
  bf16* fqp   = (bf16*)alloc((size_t)8921088 * 2);   // [16][66][66][128]
  bf16* hp    = (bf16*)alloc((size_t)17305600 * 2);  // [16][130][130][64]
  bf16* ztp   = (bf16*)alloc((size_t)2097152 * 2);   // [16][32][32][128]

  detect_dtype_kernel<<<1, 256, 0, stream>>>(d_in[0], flag);
  zero2_kernel<<<1, 64, 0, stream>>>(lacc);

  // halo-only zeroing (interiors are fully overwritten by their producers)
  zero_halo<<<517, 256, 0, stream>>>(act1p, hp, nullptr, 2, 130, 130, 8, 1081600, 16, 4128);
  zero_halo<<<781, 256, 0, stream>>>(zbp, eup, fqp, 3, 66, 66, 16, 557568, 16, 4160);
  zero_halo<<<132, 256, 0, stream>>>(zqtp, nullptr, nullptr, 1, 34, 34, 16, 147968, 16, 2112);

  // converts / repacks
  conv_bias_all<<<3, 256, 0, stream>>>(d_in[2], d_in[4], d_in[6], d_in[10],
                                       d_in[12], d_in[14], biasAll, flag);
  conv_emb<<<512, 256, 0, stream>>>(d_in[7], d_in[8], embTB, flag);
  embsq2<<<4, 256, 0, stream>>>(embTB, sqAll);
  rp_c1w<<<16, 256, 0, stream>>>(d_in[1], Wc1, flag);
  rp_conv_w<128, 64><<<512, 256, 0, stream>>>(d_in[3], Wt2, flag);
  rp_conv_w<128, 128><<<1024, 256, 0, stream>>>(d_in[5], Wtt, flag);
  rp_convt_w<128, 128><<<1024, 256, 0, stream>>>(d_in[9], Wdt, flag);
  rp_d1f<<<1024, 256, 0, stream>>>(d_in[11], Wd1f, flag);
  rp_finw<<<36, 256, 0, stream>>>(d_in[13], Wfin, flag);
  frag_pack<4, 2><<<512, 256, 0, stream>>>(Wt2, Wt2f, 131072);
  frag_pack<4, 4><<<1024, 256, 0, stream>>>(Wtt, Wttf, 262144);
  frag_pack<4, 4><<<1024, 256, 0, stream>>>(Wdt, Wdtf, 262144);

  // encoder: conv1 = im2col + MFMA GEMM
  im2col1<<<1024, 256, 0, stream>>>(d_in[0], flag, colb);
  gemm1<<<2048, 256, 0, stream>>>(colb, Wc1, beB1f, act1p);
  // conv2: NBF=2, TR=1 -> 2048 blocks
  mfma_conv<128, 64, 64, 2, 16, 64, 2><<<dim3(64, 2, 16), 256, 0, stream>>>(
      act1p, act1p, 1081600, 8320, Wt2f, beB2f, zbp + 8576, 557568, 8448, 128, 30, 0, 0);
  // conv_t: NBF=2, TR=2 -> 512 blocks
  mfma_conv<128, 128, 32, 2, 16, 128, 2><<<dim3(16, 2, 16), 256, 0, stream>>>(
      zbp, zbp, 557568, 8448, Wttf, beTf, ztp, 131072, 4096, 128, 30, 0, 0);

  // VQ top (16384 positions)
  vq_mfma<<<64, 256, 0, stream>>>(ztp, 131072, 4096, embT, sqT,
                                  zqtp + 4480, 147968, 4352, lacc + 0, 5, 10);

  // decoder_top upsample: 4 classes in one launch (nxb=4: 16 x-blocks/class)
  mfma_conv<128, 128, 32, 1, 4, 128, 2><<<dim3(64, 2, 16), 256, 0, stream>>>(
      zqtp, zqtp, 147968, 4352, Wdtf, bdTf, eup, 557568, 16896, 256, 4, 8448, 128);

  // VQ bottom (65536 positions)
  vq_mfma<<<256, 256, 0, stream>>>(zbp + 8576, 557568, 8448, embB, sqB,
                                   fqp + 8576, 557568, 8448, lacc + 1, 6, 12);

  // decoder conv d1: LDS-staged, 4 classes per block, 1024 blocks
  mfma_d1_lds<<<dim3(64, 1, 16), 256, 0, stream>>>(fqp, eup, Wd1f, bd1f, hp);

  // final convT + sigmoid via MFMA -> fp32 NCHW output
  final_convt_mfma<<<1024, 256, 0, stream>>>(hp, Wfin, bd2f, out);
  finalize_loss_kernel<<<1, 64, 0, stream>>>(lacc, out + 3145728);
}

// Round 13
// 548.854 us; speedup vs baseline: 1.4060x; 1.0085x over previous
//
#include <hip/hip_runtime.h>
#include <hip/hip_bf16.h>
#include <cstddef>

typedef __hip_bfloat16 bf16;
typedef __attribute__((ext_vector_type(8))) short short8;
typedef __attribute__((ext_vector_type(4))) float float4v;
typedef __attribute__((ext_vector_type(4))) unsigned short ushort4v;

static __device__ __forceinline__ float b2f(bf16 v) { return __bfloat162float(v); }
static __device__ __forceinline__ float bits2f(unsigned int u) { return __uint_as_float(u); }
static __device__ __forceinline__ unsigned short f2bfbits(float f) {
  bf16 h = __float2bfloat16(f);
  return *reinterpret_cast<unsigned short*>(&h);
}
static __device__ __forceinline__ float ld_any(const void* p, long i, int flag) {
  return flag ? b2f(((const bf16*)p)[i]) : ((const float*)p)[i];
}
static __device__ __forceinline__ void unpack_u4(uint4 u, float* f) {
  f[0] = bits2f(u.x << 16); f[1] = bits2f(u.x & 0xffff0000u);
  f[2] = bits2f(u.y << 16); f[3] = bits2f(u.y & 0xffff0000u);
  f[4] = bits2f(u.z << 16); f[5] = bits2f(u.z & 0xffff0000u);
  f[6] = bits2f(u.w << 16); f[7] = bits2f(u.w & 0xffff0000u);
}

// --------------------------------------------------------- dtype detection
__global__ void detect_dtype_kernel(const void* __restrict__ x, int* __restrict__ flag) {
  __shared__ int ok;
  if (threadIdx.x == 0) ok = 1;
  __syncthreads();
  float v = b2f(((const bf16*)x)[threadIdx.x]);
  if (!(v >= 0.f && v <= 1.0009765625f)) ok = 0;
  __syncthreads();
  if (threadIdx.x == 0) *flag = ok;
}

// ---------------------------------------------------------------- utilities
__global__ void zero2_kernel(float* p) {
  if (threadIdx.x < 2) p[threadIdx.x] = 0.f;
}

// zero only the 1-wide halo ring of up to 3 same-shape padded NHWC buffers.
// NOTE: valid for both row-major and parity-split-x rows: edge cells map to
// offsets 0 and (W-1)*C in both layouts, and top/bottom rows are full rows.
__global__ void zero_halo(bf16* p0, bf16* p1, bf16* p2, int np,
                          int H, int W, int C8, long imgS, int nimg, int gpi) {
  int tid = blockIdx.x * 256 + threadIdx.x;
  int total = nimg * gpi;
  int which = tid / total;
  if (which >= np) return;
  int r = tid - which * total;
  int img = r / gpi, g = r % gpi;
  int pos = g / C8, c8 = g % C8;
  int row, col;
  if (pos < W) { row = 0; col = pos; }
  else if (pos < 2 * W) { row = H - 1; col = pos - W; }
  else { int s = pos - 2 * W; row = 1 + (s >> 1); col = (s & 1) ? (W - 1) : 0; }
  bf16* base = (which == 0) ? p0 : ((which == 1) ? p1 : p2);
  uint4* dst = (uint4*)(base + (long)img * imgS + ((long)row * W + col) * (C8 * 8) + (long)c8 * 8);
  *dst = uint4{0u, 0u, 0u, 0u};
}

// all 6 conv biases -> one fp32 buffer
__global__ void conv_bias_all(const void* s2, const void* s4, const void* s6,
                              const void* s10, const void* s12, const void* s14,
                              float* __restrict__ dst, const int* __restrict__ flag) {
  int i = blockIdx.x * 256 + threadIdx.x;
  if (i >= 515) return;
  int fl = *flag;
  const void* s; int off;
  if (i < 64)       { s = s2;  off = i; }
  else if (i < 192) { s = s4;  off = i - 64; }
  else if (i < 320) { s = s6;  off = i - 192; }
  else if (i < 448) { s = s10; off = i - 320; }
  else if (i < 512) { s = s12; off = i - 448; }
  else              { s = s14; off = i - 512; }
  dst[i] = ld_any(s, off, fl);
}

// both codebooks -> contiguous bf16 [1024][128]
__global__ void conv_emb(const void* __restrict__ sT, const void* __restrict__ sB,
                         bf16* __restrict__ dst, const int* __restrict__ flag) {
  int i = blockIdx.x * 256 + threadIdx.x;   // 131072
  int fl = *flag;
  const void* s = (i < 65536) ? sT : sB;
  int off = i & 65535;
  dst[i] = fl ? ((const bf16*)s)[off] : __float2bfloat16(((const float*)s)[off]);
}

__global__ void embsq2(const bf16* __restrict__ embTB, float* __restrict__ sqAll) {
  int k = blockIdx.x * blockDim.x + threadIdx.x;
  if (k >= 1024) return;
  float s = 0.f;
  const bf16* e = embTB + (long)k * 128;
  for (int c = 0; c < 128; ++c) { float v = b2f(e[c]); s = fmaf(v, v, s); }
  sqAll[k] = s;
}

// conv1 weights [64][3][4][4] -> [co][k] bf16, K padded 48->64 with zeros
__global__ void rp_c1w(const void* __restrict__ src, bf16* __restrict__ dst,
                       const int* __restrict__ flag) {
  int i = blockIdx.x * blockDim.x + threadIdx.x;   // 64*64
  if (i >= 4096) return;
  int co = i >> 6, k = i & 63;
  float v = (k < 48) ? ld_any(src, co * 48 + k, *flag) : 0.f;
  dst[i] = __float2bfloat16(v);
}

// weights OIHW [CO][CI][4][4] -> [tap=kh*4+kw][co][ci] bf16
template <int CO, int CI>
__global__ void rp_conv_w(const void* __restrict__ src, bf16* __restrict__ dst,
                          const int* __restrict__ flag) {
  const int N = CO * CI * 16;
  int i = blockIdx.x * blockDim.x + threadIdx.x;
  if (i >= N) return;
  int co = i / (CI * 16);
  int rem = i % (CI * 16);
  int ci = rem >> 4;
  int k = rem & 15;
  dst[((long)k * CO + co) * CI + ci] = __float2bfloat16(ld_any(src, i, *flag));
}

// convT weights [CI][CO][4][4] -> [class pq][tap st][co][ci] bf16
template <int CI, int CO>
__global__ void rp_convt_w(const void* __restrict__ src, bf16* __restrict__ dst,
                           const int* __restrict__ flag) {
  const int N = CI * CO * 16;
  int i = blockIdx.x * blockDim.x + threadIdx.x;
  if (i >= N) return;
  int ci = i / (CO * 16);
  int rem = i % (CO * 16);
  int co = rem >> 4;
  int k = rem & 15;
  int kh = k >> 2, kw = k & 3;
  int p = (kh + 1) & 1, s = (kh - 1 + p) >> 1;
  int q = (kw + 1) & 1, t = (kw - 1 + q) >> 1;
  long d = (((long)(p * 2 + q) * 4 + (s * 2 + t)) * CO + co) * CI + ci;
  dst[d] = __float2bfloat16(ld_any(src, i, *flag));
}

// [tg][co][ci] -> fragment order [((tg*MC+mc)*KC+kc)*2+j][ln][quad*8]
template <int MC, int KC>
__global__ void frag_pack(const bf16* __restrict__ src, bf16* __restrict__ dst, int total) {
  int i = blockIdx.x * 256 + threadIdx.x;
  if (i >= total) return;
  int low = i & 511;
  int ln = low >> 5, cl = low & 31;
  int c2 = i >> 9;
  int j = c2 & 1;
  int c3 = c2 >> 1;
  int kc = c3 & (KC - 1);
  int c4 = c3 / KC;
  int mc = c4 & (MC - 1);
  int tg = c4 / MC;
  int co = mc * 32 + j * 16 + ln;
  int ci = kc * 32 + cl;
  dst[i] = src[((long)tg * (MC * 32) + co) * (KC * 32) + ci];
}

// d1 weights [256ci][64co][4][4] -> frag [(((cls*4+t)*8+kc)*4+j)][ln][quad*8]
__global__ void rp_d1f(const void* __restrict__ src, bf16* __restrict__ dst,
                       const int* __restrict__ flag) {
  int i = blockIdx.x * 256 + threadIdx.x;   // 262144
  if (i >= 262144) return;
  int low = i & 511;
  int ln = low >> 5, cl = low & 31;
  int c2 = i >> 9;
  int j = c2 & 3;
  int kc = (c2 >> 2) & 7;
  int t = (c2 >> 5) & 3;
  int cls = c2 >> 7;
  int p = cls >> 1, q = cls & 1;
  int s = t >> 1, t2 = t & 1;
  int kh = 2 * s + 1 - p, kw = 2 * t2 + 1 - q;
  int co = j * 16 + ln, ci = kc * 32 + cl;
  dst[i] = __float2bfloat16(ld_any(src, (long)ci * 1024 + co * 16 + kh * 4 + kw, *flag));
}

// final convT weights [64ci][3co][4][4] -> A[m=cls*4+co][d=dy*3+dx][64ci]
__global__ void rp_finw(const void* __restrict__ src, bf16* __restrict__ dst,
                        const int* __restrict__ flag) {
  int i = blockIdx.x * blockDim.x + threadIdx.x;   // 16*576 = 9216
  if (i >= 9216) return;
  int m = i / 576, rem = i % 576;
  int d = rem >> 6, ci = rem & 63;
  int cls = m >> 2, co = m & 3;
  int p = cls >> 1, q = cls & 1;
  int dy = d / 3, dx = d % 3;
  int s = p - dy + 1, t = q - dx + 1;
  float v = 0.f;
  if (co < 3 && s >= 0 && s <= 1 && t >= 0 && t <= 1) {
    int kh = 2 * s + 1 - p, kw = 2 * t + 1 - q;
    v = ld_any(src, ci * 48 + co * 16 + kh * 4 + kw, *flag);
  }
  dst[i] = __float2bfloat16(v);
}

// -------------------- conv1 as GEMM: im2col (K padded to 64) + MFMA GEMM
__global__ __launch_bounds__(256) void im2col1(const void* __restrict__ x,
                                               const int* __restrict__ flag,
                                               bf16* __restrict__ col) {
  int tid = blockIdx.x * 256 + threadIdx.x;   // 16*128*128
  int ow = tid & 127; int t = tid >> 7;
  int oh = t & 127; int b = t >> 7;
  int fl = *flag;
  int ih0 = oh * 2 - 1, iw0 = ow * 2 - 1;
  unsigned short vals[64];
  #pragma unroll
  for (int j = 48; j < 64; ++j) vals[j] = 0;
  #pragma unroll
  for (int ci = 0; ci < 3; ++ci) {
    long pbase = ((long)(b * 3 + ci)) << 16;
    #pragma unroll
    for (int kh = 0; kh < 4; ++kh) {
      int ih = ih0 + kh;
      bool okh = (unsigned)ih < 256u;
      long rbase = pbase + ((long)ih << 8);
      #pragma unroll
      for (int kw = 0; kw < 4; ++kw) {
        int iw = iw0 + kw;
        float v = (okh && (unsigned)iw < 256u) ? ld_any(x, rbase + iw, fl) : 0.f;
        vals[ci * 16 + kh * 4 + kw] = f2bfbits(v);
      }
    }
  }
  uint4* dst = (uint4*)(col + (long)tid * 64);
  const uint4* s = (const uint4*)vals;
  #pragma unroll
  for (int j = 0; j < 8; ++j) dst[j] = s[j];
}

// M=64 (co), K=64, N=262144; bias+relu; store parity-split padded NHWC
__global__ __launch_bounds__(256) void gemm1(const bf16* __restrict__ col,
                                             const bf16* __restrict__ w,
                                             const float* __restrict__ bias,
                                             bf16* __restrict__ act1p) {
  const int lane = threadIdx.x & 63, wv = threadIdx.x >> 6;
  const int wm = wv & 1, wn = wv >> 1;
  const int ln = lane & 15, quad = lane >> 4;
  const int n0 = blockIdx.x * 128 + wn * 64;
  float4v acc[2][4];
  #pragma unroll
  for (int i = 0; i < 2; ++i)
    #pragma unroll
    for (int j = 0; j < 4; ++j) acc[i][j] = {0.f, 0.f, 0.f, 0.f};
  #pragma unroll
  for (int kc = 0; kc < 2; ++kc) {
    const bf16* wk = w + (wm * 32 + ln) * 64 + kc * 32 + quad * 8;
    short8 a0 = *(const short8*)(wk);
    short8 a1 = *(const short8*)(wk + 16 * 64);
    #pragma unroll
    for (int bf = 0; bf < 4; ++bf) {
      short8 bv = *(const short8*)(col + (long)(n0 + bf * 16 + ln) * 64 + kc * 32 + quad * 8);
      acc[0][bf] = __builtin_amdgcn_mfma_f32_16x16x32_bf16(a0, bv, acc[0][bf], 0, 0, 0);
      acc[1][bf] = __builtin_amdgcn_mfma_f32_16x16x32_bf16(a1, bv, acc[1][bf], 0, 0, 0);
    }
  }
  #pragma unroll
  for (int mf = 0; mf < 2; ++mf) {
    int coB = wm * 32 + mf * 16 + quad * 4;
    float4v bv4 = *(const float4v*)(bias + coB);
    #pragma unroll
    for (int bf = 0; bf < 4; ++bf) {
      int n = n0 + bf * 16 + ln;
      int ow = n & 127; int t2 = n >> 7;
      int oh = t2 & 127; int b = t2 >> 7;
      int xx = ow + 1;   // parity-split column
      long oaddr = ((long)(b * 130 + oh + 1)) * 8320 +
                   (long)(((xx & 1) * 65) + (xx >> 1)) * 64 + coB;
      float4v v = acc[mf][bf];
      ushort4v o;
      #pragma unroll
      for (int e = 0; e < 4; ++e) o[e] = f2bfbits(fmaxf(v[e] + bv4[e], 0.f));
      *(ushort4v*)(act1p + oaddr) = o;
    }
  }
}

// ------------------------------------------- MFMA implicit-GEMM tap conv
// PXW>0: input rows are parity-split-x with half-width PXW (S=2 only) ->
// B-frag lane addresses become contiguous in c. oPXW>0: output rows are
// parity-split (base passed at col 0; interior col = cc+1).
template <int COUT, int CINT, int TC, int S, int NT, int INC, int NBF, int PXW>
__global__ __launch_bounds__(256) void mfma_conv(
    const bf16* __restrict__ in1, const bf16* __restrict__ in2,
    long inImgS, int inRowS,
    const bf16* __restrict__ wf, const float* __restrict__ bias,
    bf16* __restrict__ outp, long outImgS, int oRS, int oCS,
    int nxb, long po, long qo, int oPXW) {
  constexpr int TR = (2 * NBF * 16) / TC;
  constexpr int KC = CINT / 32;
  constexpr int MC = COUT / 32;
  constexpr int KSPLIT = (CINT > INC) ? (INC / 32) : KC;
  const int lane = threadIdx.x & 63;
  const int wv = threadIdx.x >> 6;
  const int wm = wv & 1, wn = wv >> 1;
  const int ln = lane & 15, quad = lane >> 4;
  const int cls = blockIdx.x >> nxb;
  const int xb = blockIdx.x & ((1u << nxb) - 1u);
  const int mTile = blockIdx.y * 64;
  const int mc = blockIdx.y * 2 + wm;
  const int oh0 = xb * TR;
  const int b = blockIdx.z;
  const int p = cls >> 1, q = cls & 1;
  const long ooff = (long)(p + 1) * po + (long)(q + 1) * qo;

  long posOff[NBF];
  int rr[NBF], cc[NBF];
  #pragma unroll
  for (int bf = 0; bf < NBF; ++bf) {
    int n = wn * (NBF * 16) + bf * 16 + ln;
    int r = n / TC, c = n % TC;
    rr[bf] = r; cc[bf] = c;
    posOff[bf] = (long)(S * (oh0 + r)) * inRowS +
                 (PXW ? (long)c * INC : (long)(S * c) * INC);
  }
  const bf16* inb1 = in1 + (long)b * inImgS;
  const bf16* inb2 = in2 + (long)b * inImgS;

  float4v acc[2][NBF];
  #pragma unroll
  for (int i = 0; i < 2; ++i)
    #pragma unroll
    for (int j = 0; j < NBF; ++j) acc[i][j] = {0.f, 0.f, 0.f, 0.f};

  for (int t = 0; t < NT; ++t) {
    int dy, dx;
    if (S == 2) { dy = t >> 2; dx = t & 3; }
    else        { dy = p - (t >> 1) + 1; dx = q - (t & 1) + 1; }
    const int dxo = PXW ? ((dx & 1) * PXW + (dx >> 1)) : dx;
    const long tapOff = (long)dy * inRowS + (long)dxo * INC;
    const bf16* wt = wf + ((long)(cls * NT + t) * MC + mc) * (KC * 1024) + ln * 32 + quad * 8;
    #pragma unroll
    for (int kc = 0; kc < KC; ++kc) {
      short8 a0 = *(const short8*)(wt + kc * 1024);
      short8 a1 = *(const short8*)(wt + kc * 1024 + 512);
      const bf16* bp = (kc < KSPLIT) ? inb1 : inb2;
      int kOff = (kc < KSPLIT ? kc : kc - KSPLIT) * 32 + quad * 8;
      #pragma unroll
      for (int bf = 0; bf < NBF; ++bf) {
        short8 bv = *(const short8*)(bp + posOff[bf] + tapOff + kOff);
        acc[0][bf] = __builtin_amdgcn_mfma_f32_16x16x32_bf16(a0, bv, acc[0][bf], 0, 0, 0);
        acc[1][bf] = __builtin_amdgcn_mfma_f32_16x16x32_bf16(a1, bv, acc[1][bf], 0, 0, 0);
      }
    }
  }

  bf16* outb = outp + (long)b * outImgS + ooff;
  #pragma unroll
  for (int mf = 0; mf < 2; ++mf) {
    int coB = mTile + wm * 32 + mf * 16 + quad * 4;
    float4v bv4 = *(const float4v*)(bias + coB);
    #pragma unroll
    for (int bf = 0; bf < NBF; ++bf) {
      float4v v = acc[mf][bf];
      ushort4v o;
      #pragma unroll
      for (int e = 0; e < 4; ++e)
        o[e] = f2bfbits(fmaxf(v[e] + bv4[e], 0.f));
      long coff = oPXW ? (long)((((cc[bf] + 1) & 1) * oPXW) + ((cc[bf] + 1) >> 1)) * oCS
                       : (long)cc[bf] * oCS;
      long oaddr = (long)(oh0 + rr[bf]) * oRS + coff + coB;
      *(ushort4v*)(outb + oaddr) = o;
    }
  }
}

// ------ d1 (concat 256 -> 64) with LDS-staged input, 4 classes per block
__global__ __launch_bounds__(256) void mfma_d1_lds(
    const bf16* __restrict__ in1, const bf16* __restrict__ in2,
    const bf16* __restrict__ wf, const float* __restrict__ bias,
    bf16* __restrict__ outp) {
  __shared__ short8 lds8[198 * 17];   // 53856 B
  const int lane = threadIdx.x & 63, wv = threadIdx.x >> 6;
  const int ln = lane & 15, quad = lane >> 4;
  const int r = blockIdx.x;          // output class-row 0..63
  const int b = blockIdx.z;
  const int cls = wv, p = cls >> 1, q = cls & 1;

  const bf16* src1 = in1 + (long)b * 557568 + (long)r * 8448;  // rows r..r+2
  const bf16* src2 = in2 + (long)b * 557568 + (long)r * 8448;

  float4v acc[4][4];
  #pragma unroll
  for (int j = 0; j < 4; ++j)
    #pragma unroll
    for (int bf = 0; bf < 4; ++bf) acc[j][bf] = {0.f, 0.f, 0.f, 0.f};

  #pragma unroll
  for (int phase = 0; phase < 2; ++phase) {
    const bf16* src = phase ? src2 : src1;
    __syncthreads();
    for (int i = threadIdx.x; i < 3168; i += 256) {   // 198 pos x 16 chunks
      int pos = i >> 4, j = i & 15;
      lds8[pos * 17 + j] = *(const short8*)(src + (long)pos * 128 + j * 8);
    }
    __syncthreads();
    #pragma unroll
    for (int t = 0; t < 4; ++t) {
      int dy = p - (t >> 1) + 1, dx = q - (t & 1) + 1;
      const bf16* wt = wf + (long)(cls * 4 + t) * 16384 + (long)(phase * 4) * 2048 +
                       ln * 32 + quad * 8;
      const int lbase = (dy * 66 + dx) * 17 + quad;
      #pragma unroll
      for (int kc = 0; kc < 4; ++kc) {
        const bf16* wk = wt + kc * 2048;
        short8 a0 = *(const short8*)(wk);
        short8 a1 = *(const short8*)(wk + 512);
        short8 a2 = *(const short8*)(wk + 1024);
        short8 a3 = *(const short8*)(wk + 1536);
        #pragma unroll
        for (int bf = 0; bf < 4; ++bf) {
          short8 bv = lds8[lbase + kc * 4 + (bf * 16 + ln) * 17];
          acc[0][bf] = __builtin_amdgcn_mfma_f32_16x16x32_bf16(a0, bv, acc[0][bf], 0, 0, 0);
          acc[1][bf] = __builtin_amdgcn_mfma_f32_16x16x32_bf16(a1, bv, acc[1][bf], 0, 0, 0);
          acc[2][bf] = __builtin_amdgcn_mfma_f32_16x16x32_bf16(a2, bv, acc[2][bf], 0, 0, 0);
          acc[3][bf] = __builtin_amdgcn_mfma_f32_16x16x32_bf16(a3, bv, acc[3][bf], 0, 0, 0);
        }
      }
    }
  }

  bf16* outb = outp + (long)b * 1081600 + (long)(p + 1) * 8320 + (long)(q + 1) * 64 +
               (long)r * 16640;
  #pragma unroll
  for (int j = 0; j < 4; ++j) {
    int co = j * 16 + quad * 4;
    float4v bv4 = *(const float4v*)(bias + co);
    #pragma unroll
    for (int bf = 0; bf < 4; ++bf) {
      float4v v = acc[j][bf];
      ushort4v o;
      #pragma unroll
      for (int e = 0; e < 4; ++e)
        o[e] = f2bfbits(fmaxf(v[e] + bv4[e], 0.f));
      *(ushort4v*)(outb + (long)(bf * 16 + ln) * 128 + co) = o;
    }
  }
}

// ---------------------------------------------------- VQ via MFMA GEMM
// ipxw>0: input rows are parity-split-x with half-width ipxw (base at col 0,
// interior col = x+1). Output zq always row-major.
__global__ __launch_bounds__(256) void vq_mfma(
    const bf16* __restrict__ z, long zImgS, int zRowS,
    const bf16* __restrict__ emb, const float* __restrict__ embsq,
    bf16* __restrict__ zq, long qImgS, int qRowS,
    float* __restrict__ loss_acc, int wb, int hwb, int ipxw) {
  const int lane = threadIdx.x & 63, wv = threadIdx.x >> 6;
  const int ln = lane & 15, quad = lane >> 4;
  const int base = blockIdx.x * 256 + wv * 64;

  short8 bfrag[4][4];
  #pragma unroll
  for (int bf = 0; bf < 4; ++bf) {
    int n = base + bf * 16 + ln;
    int b = n >> hwb;
    int rem = n & ((1 << hwb) - 1);
    int y = rem >> wb, x = rem & ((1 << wb) - 1);
    int xcol = ipxw ? ((((x + 1) & 1) * ipxw) + ((x + 1) >> 1)) : x;
    const bf16* zrow = z + (long)b * zImgS + (long)y * zRowS + (long)xcol * 128;
    #pragma unroll
    for (int kc = 0; kc < 4; ++kc)
      bfrag[bf][kc] = *(const short8*)(zrow + kc * 32 + quad * 8);
  }

  float best0 = 3.4e38f, best1 = 3.4e38f, best2 = 3.4e38f, best3 = 3.4e38f;
  int bk0 = 0, bk1 = 0, bk2 = 0, bk3 = 0;
  for (int ct = 0; ct < 32; ++ct) {
    const bf16* erow = emb + (long)(ct * 16 + ln) * 128 + quad * 8;
    short8 a0 = *(const short8*)(erow);
    short8 a1 = *(const short8*)(erow + 32);
    short8 a2 = *(const short8*)(erow + 64);
    short8 a3 = *(const short8*)(erow + 96);
    float4v sq4 = *(const float4v*)(embsq + ct * 16 + quad * 4);
    #pragma unroll
    for (int bf = 0; bf < 4; ++bf) {
      float4v acc = {0.f, 0.f, 0.f, 0.f};
      acc = __builtin_amdgcn_mfma_f32_16x16x32_bf16(a0, bfrag[bf][0], acc, 0, 0, 0);
      acc = __builtin_amdgcn_mfma_f32_16x16x32_bf16(a1, bfrag[bf][1], acc, 0, 0, 0);
      acc = __builtin_amdgcn_mfma_f32_16x16x32_bf16(a2, bfrag[bf][2], acc, 0, 0, 0);
      acc = __builtin_amdgcn_mfma_f32_16x16x32_bf16(a3, bfrag[bf][3], acc, 0, 0, 0);
      int kb = ct * 16 + quad * 4;
      #pragma unroll
      for (int r = 0; r < 4; ++r) {
        float s = fmaf(-2.f, acc[r], sq4[r]);
        if (bf == 0) { if (s < best0) { best0 = s; bk0 = kb + r; } }
        if (bf == 1) { if (s < best1) { best1 = s; bk1 = kb + r; } }
        if (bf == 2) { if (s < best2) { best2 = s; bk2 = kb + r; } }
        if (bf == 3) { if (s < best3) { best3 = s; bk3 = kb + r; } }
      }
    }
  }
  float bs[4] = {best0, best1, best2, best3};
  int bk[4] = {bk0, bk1, bk2, bk3};
  #pragma unroll
  for (int bf = 0; bf < 4; ++bf) {
    #pragma unroll
    for (int m = 16; m <= 32; m <<= 1) {
      float os = __shfl_xor(bs[bf], m, 64);
      int ok = __shfl_xor(bk[bf], m, 64);
      if (os < bs[bf] || (os == bs[bf] && ok < bk[bf])) { bs[bf] = os; bk[bf] = ok; }
    }
  }
  int myk = (quad == 0) ? bk[0] : (quad == 1) ? bk[1] : (quad == 2) ? bk[2] : bk[3];
  int n = base + quad * 16 + ln;
  int b = n >> hwb;
  int rem = n & ((1 << hwb) - 1);
  int y = rem >> wb, x = rem & ((1 << wb) - 1);
  int xcol = ipxw ? ((((x + 1) & 1) * ipxw) + ((x + 1) >> 1)) : x;
  const uint4* zr = (const uint4*)(z + (long)b * zImgS + (long)y * zRowS + (long)xcol * 128);
  uint4* qr = (uint4*)(zq + (long)b * qImgS + (long)y * qRowS + (long)x * 128);
  const uint4* er = (const uint4*)(emb + (long)myk * 128);
  float lsum = 0.f;
  #pragma unroll
  for (int j = 0; j < 16; ++j) {
    uint4 ue = er[j];
    uint4 uz = zr[j];
    qr[j] = ue;
    float ev[8], zv[8];
    unpack_u4(ue, ev);
    unpack_u4(uz, zv);
    #pragma unroll
    for (int e = 0; e < 8; ++e) {
      float dv = ev[e] - zv[e];
      lsum = fmaf(dv, dv, lsum);
    }
  }
  for (int o = 32; o > 0; o >>= 1) lsum += __shfl_down(lsum, o, 64);
  if (lane == 0) atomicAdd(loss_acc, lsum);
}

// --------------------- final convT(64->3)+sigmoid via class-packed MFMA
__global__ __launch_bounds__(256) void final_convt_mfma(
    const bf16* __restrict__ hp, const bf16* __restrict__ wfin,
    const float* __restrict__ bf_, float* __restrict__ out) {
  const int lane = threadIdx.x & 63, wv = threadIdx.x >> 6;
  const int ln = lane & 15, quad = lane >> 4;
  const int base = blockIdx.x * 256 + wv * 64;   // 262144 positions total

  short8 afr[18];
  #pragma unroll
  for (int kc = 0; kc < 18; ++kc)
    afr[kc] = *(const short8*)(wfin + ln * 576 + kc * 32 + quad * 8);

  float4v acc[4];
  #pragma unroll
  for (int bf = 0; bf < 4; ++bf) acc[bf] = {0.f, 0.f, 0.f, 0.f};

  #pragma unroll
  for (int bf = 0; bf < 4; ++bf) {
    int n = base + bf * 16 + ln;
    int xx = n & 127, y = (n >> 7) & 127, b = n >> 14;
    const bf16* hb = hp + (long)b * 1081600 + (long)y * 8320 + (long)xx * 64;
    #pragma unroll
    for (int kc = 0; kc < 18; ++kc) {
      int d = kc >> 1;
      const bf16* bp = hb + (long)(d / 3) * 8320 + (d % 3) * 64 + (kc & 1) * 32 + quad * 8;
      short8 bv = *(const short8*)bp;
      acc[bf] = __builtin_amdgcn_mfma_f32_16x16x32_bf16(afr[kc], bv, acc[bf], 0, 0, 0);
    }
  }

  const int p = quad >> 1, q = quad & 1;
  float b0 = bf_[0], b1 = bf_[1], b2 = bf_[2];
  #pragma unroll
  for (int bf = 0; bf < 4; ++bf) {
    int n = base + bf * 16 + ln;
    int xx = n & 127, y = (n >> 7) & 127, b = n >> 14;
    long ob = (long)b * 196608 + (long)(2 * y + p) * 256 + (2 * xx + q);
    float v0 = acc[bf][0] + b0, v1 = acc[bf][1] + b1, v2 = acc[bf][2] + b2;
    out[ob]          = 1.f / (1.f + expf(-v0));
    out[ob + 65536]  = 1.f / (1.f + expf(-v1));
    out[ob + 131072] = 1.f / (1.f + expf(-v2));
  }
}

__global__ void finalize_loss_kernel(const float* __restrict__ lacc, float* __restrict__ out) {
  if (threadIdx.x == 0) {
    float lt = lacc[0] * (1.5f / 2097152.f);
    float lb = lacc[1] * (1.5f / 8388608.f);
    *out = lt + lb;
  }
}

// ------------------------------------------------------------------ launch
extern "C" void kernel_launch(void* const* d_in, const int* in_sizes, int n_in,
                              void* d_out, int out_size, void* d_ws, size_t ws_size,
                              hipStream_t stream) {
  float* out = (float*)d_out;
  char* base = (char*)d_ws;
  size_t off = 0;
  auto alloc = [&](size_t bytes) {
    void* pp = base + off;
    off = (off + bytes + 255) & ~(size_t)255;
    return pp;
  };

  int* flag = (int*)alloc(256);
  float* biasAll = (float*)alloc(515 * 4);
  float* beB1f = biasAll + 0;
  float* beB2f = biasAll + 64;
  float* beTf  = biasAll + 192;
  float* bdTf  = biasAll + 320;
  float* bd1f  = biasAll + 448;
  float* bd2f  = biasAll + 512;
  float* sqAll = (float*)alloc(1024 * 4);
  float* sqT = sqAll, *sqB = sqAll + 512;
  float* lacc = (float*)alloc(2 * 4);
  bf16* Wc1  = (bf16*)alloc((size_t)4096 * 2);
  bf16* Wt2  = (bf16*)alloc((size_t)131072 * 2);
  bf16* Wtt  = (bf16*)alloc((size_t)262144 * 2);
  bf16* Wdt  = (bf16*)alloc((size_t)262144 * 2);
  bf16* Wt2f = (bf16*)alloc((size_t)131072 * 2);
  bf16* Wttf = (bf16*)alloc((size_t)262144 * 2);
  bf16* Wdtf = (bf16*)alloc((size_t)262144 * 2);
  bf16* Wd1f = (bf16*)alloc((size_t)262144 * 2);
  bf16* Wfin = (bf16*)alloc((size_t)9216 * 2);
  bf16* embTB = (bf16*)alloc((size_t)131072 * 2);
  bf16* embT = embTB, *embB = embTB + 65536;
  bf16* colb = (bf16*)alloc((size_t)16777216 * 2);   // im2col [262144][64]
  bf16* act1p = (bf16*)alloc((size_t)17305600 * 2);  // [16][130][2][65][64] parity
  bf16* zbp   = (bf16*)alloc((size_t)8921088 * 2);   // [16][66][2][33][128] parity
  bf16* zqtp  = (bf16*)alloc((size_t)2367488 * 2);   // [16][34][34][128]
  bf16* eup   = (bf16*)alloc((size_t)8921088 * 2);   // [16][66][66][128]
  bf16* fqp   = (bf16*)alloc((size_t)8921088 * 2);   // [16][66][66][128]
  bf16* hp    = (bf16*)alloc((size_t)17305600 * 2);  // [16][130][130][64]
  bf16* ztp   = (bf16*)alloc((size_t)2097152 * 2);   // [16][32][32][128]

  detect_dtype_kernel<<<1, 256, 0, stream>>>(d_in[0], flag);
  zero2_kernel<<<1, 64, 0, stream>>>(lacc);

  // halo-only zeroing (edge offsets identical in parity-split layout)
  zero_halo<<<517, 256, 0, stream>>>(act1p, hp, nullptr, 2, 130, 130, 8, 1081600, 16, 4128);
  zero_halo<<<781, 256, 0, stream>>>(zbp, eup, fqp, 3, 66, 66, 16, 557568, 16, 4160);
  zero_halo<<<132, 256, 0, stream>>>(zqtp, nullptr, nullptr, 1, 34, 34, 16, 147968, 16, 2112);

  // converts / repacks
  conv_bias_all<<<3, 256, 0, stream>>>(d_in[2], d_in[4], d_in[6], d_in[10],
                                       d_in[12], d_in[14], biasAll, flag);
  conv_emb<<<512, 256, 0, stream>>>(d_in[7], d_in[8], embTB, flag);
  embsq2<<<4, 256, 0, stream>>>(embTB, sqAll);
  rp_c1w<<<16, 256, 0, stream>>>(d_in[1], Wc1, flag);
  rp_conv_w<128, 64><<<512, 256, 0, stream>>>(d_in[3], Wt2, flag);
  rp_conv_w<128, 128><<<1024, 256, 0, stream>>>(d_in[5], Wtt, flag);
  rp_convt_w<128, 128><<<1024, 256, 0, stream>>>(d_in[9], Wdt, flag);
  rp_d1f<<<1024, 256, 0, stream>>>(d_in[11], Wd1f, flag);
  rp_finw<<<36, 256, 0, stream>>>(d_in[13], Wfin, flag);
  frag_pack<4, 2><<<512, 256, 0, stream>>>(Wt2, Wt2f, 131072);
  frag_pack<4, 4><<<1024, 256, 0, stream>>>(Wtt, Wttf, 262144);
  frag_pack<4, 4><<<1024, 256, 0, stream>>>(Wdt, Wdtf, 262144);

  // encoder: conv1 = im2col + MFMA GEMM (parity-split store)
  im2col1<<<1024, 256, 0, stream>>>(d_in[0], flag, colb);
  gemm1<<<2048, 256, 0, stream>>>(colb, Wc1, beB1f, act1p);
  // conv2: PXW=65 (act1p parity), output zbp parity (oPXW=33, base row1 col0)
  mfma_conv<128, 64, 64, 2, 16, 64, 2, 65><<<dim3(64, 2, 16), 256, 0, stream>>>(
      act1p, act1p, 1081600, 8320, Wt2f, beB2f, zbp + 8448, 557568, 8448, 128, 30, 0, 0, 33);
  // conv_t: PXW=33 (zbp parity), output ztp row-major
  mfma_conv<128, 128, 32, 2, 16, 128, 2, 33><<<dim3(16, 2, 16), 256, 0, stream>>>(
      zbp, zbp, 557568, 8448, Wttf, beTf, ztp, 131072, 4096, 128, 30, 0, 0, 0);

  // VQ top (16384 positions, row-major)
  vq_mfma<<<64, 256, 0, stream>>>(ztp, 131072, 4096, embT, sqT,
                                  zqtp + 4480, 147968, 4352, lacc + 0, 5, 10, 0);

  // decoder_top upsample: 4 classes in one launch (row-major in/out)
  mfma_conv<128, 128, 32, 1, 4, 128, 2, 0><<<dim3(64, 2, 16), 256, 0, stream>>>(
      zqtp, zqtp, 147968, 4352, Wdtf, bdTf, eup, 557568, 16896, 256, 4, 8448, 128, 0);

  // VQ bottom (65536 positions; zbp parity-split input, fqp row-major out)
  vq_mfma<<<256, 256, 0, stream>>>(zbp + 8448, 557568, 8448, embB, sqB,
                                   fqp + 8576, 557568, 8448, lacc + 1, 6, 12, 33);

  // decoder conv d1: LDS-staged, 4 classes per block, 1024 blocks
  mfma_d1_lds<<<dim3(64, 1, 16), 256, 0, stream>>>(fqp, eup, Wd1f, bd1f, hp);

  // final convT + sigmoid via MFMA -> fp32 NCHW output
  final_convt_mfma<<<1024, 256, 0, stream>>>(hp, Wfin, bd2f, out);
  finalize_loss_kernel<<<1, 64, 0, stream>>>(lacc, out + 3145728);
}

// Round 14
// 496.431 us; speedup vs baseline: 1.5545x; 1.1056x over previous
//
#include <hip/hip_runtime.h>
#include <hip/hip_bf16.h>
#include <cstddef>

typedef __hip_bfloat16 bf16;
typedef __attribute__((ext_vector_type(8))) short short8;
typedef __attribute__((ext_vector_type(4))) float float4v;
typedef __attribute__((ext_vector_type(4))) unsigned short ushort4v;

static __device__ __forceinline__ float b2f(bf16 v) { return __bfloat162float(v); }
static __device__ __forceinline__ float bits2f(unsigned int u) { return __uint_as_float(u); }
static __device__ __forceinline__ unsigned short f2bfbits(float f) {
  bf16 h = __float2bfloat16(f);
  return *reinterpret_cast<unsigned short*>(&h);
}
static __device__ __forceinline__ float ld_any(const void* p, long i, int flag) {
  return flag ? b2f(((const bf16*)p)[i]) : ((const float*)p)[i];
}
static __device__ __forceinline__ void unpack_u4(uint4 u, float* f) {
  f[0] = bits2f(u.x << 16); f[1] = bits2f(u.x & 0xffff0000u);
  f[2] = bits2f(u.y << 16); f[3] = bits2f(u.y & 0xffff0000u);
  f[4] = bits2f(u.z << 16); f[5] = bits2f(u.z & 0xffff0000u);
  f[6] = bits2f(u.w << 16); f[7] = bits2f(u.w & 0xffff0000u);
}

// --------------------------------------------------------- dtype detection
__global__ void detect_dtype_kernel(const void* __restrict__ x, int* __restrict__ flag) {
  __shared__ int ok;
  if (threadIdx.x == 0) ok = 1;
  __syncthreads();
  float v = b2f(((const bf16*)x)[threadIdx.x]);
  if (!(v >= 0.f && v <= 1.0009765625f)) ok = 0;
  __syncthreads();
  if (threadIdx.x == 0) *flag = ok;
}

// ---------------------------------------------------------------- utilities
__global__ void zero2_kernel(float* p) {
  if (threadIdx.x < 2) p[threadIdx.x] = 0.f;
}

// zero only the 1-wide halo ring of up to 3 same-shape padded NHWC buffers.
__global__ void zero_halo(bf16* p0, bf16* p1, bf16* p2, int np,
                          int H, int W, int C8, long imgS, int nimg, int gpi) {
  int tid = blockIdx.x * 256 + threadIdx.x;
  int total = nimg * gpi;
  int which = tid / total;
  if (which >= np) return;
  int r = tid - which * total;
  int img = r / gpi, g = r % gpi;
  int pos = g / C8, c8 = g % C8;
  int row, col;
  if (pos < W) { row = 0; col = pos; }
  else if (pos < 2 * W) { row = H - 1; col = pos - W; }
  else { int s = pos - 2 * W; row = 1 + (s >> 1); col = (s & 1) ? (W - 1) : 0; }
  bf16* base = (which == 0) ? p0 : ((which == 1) ? p1 : p2);
  uint4* dst = (uint4*)(base + (long)img * imgS + ((long)row * W + col) * (C8 * 8) + (long)c8 * 8);
  *dst = uint4{0u, 0u, 0u, 0u};
}

// all 6 conv biases -> one fp32 buffer
__global__ void conv_bias_all(const void* s2, const void* s4, const void* s6,
                              const void* s10, const void* s12, const void* s14,
                              float* __restrict__ dst, const int* __restrict__ flag) {
  int i = blockIdx.x * 256 + threadIdx.x;
  if (i >= 515) return;
  int fl = *flag;
  const void* s; int off;
  if (i < 64)       { s = s2;  off = i; }
  else if (i < 192) { s = s4;  off = i - 64; }
  else if (i < 320) { s = s6;  off = i - 192; }
  else if (i < 448) { s = s10; off = i - 320; }
  else if (i < 512) { s = s12; off = i - 448; }
  else              { s = s14; off = i - 512; }
  dst[i] = ld_any(s, off, fl);
}

// both codebooks -> contiguous bf16 [1024][128]
__global__ void conv_emb(const void* __restrict__ sT, const void* __restrict__ sB,
                         bf16* __restrict__ dst, const int* __restrict__ flag) {
  int i = blockIdx.x * 256 + threadIdx.x;   // 131072
  int fl = *flag;
  const void* s = (i < 65536) ? sT : sB;
  int off = i & 65535;
  dst[i] = fl ? ((const bf16*)s)[off] : __float2bfloat16(((const float*)s)[off]);
}

__global__ void embsq2(const bf16* __restrict__ embTB, float* __restrict__ sqAll) {
  int k = blockIdx.x * blockDim.x + threadIdx.x;
  if (k >= 1024) return;
  float s = 0.f;
  const bf16* e = embTB + (long)k * 128;
  for (int c = 0; c < 128; ++c) { float v = b2f(e[c]); s = fmaf(v, v, s); }
  sqAll[k] = s;
}

// conv1 weights [64][3][4][4] -> [co][k] bf16, K padded 48->64 with zeros
__global__ void rp_c1w(const void* __restrict__ src, bf16* __restrict__ dst,
                       const int* __restrict__ flag) {
  int i = blockIdx.x * blockDim.x + threadIdx.x;   // 64*64
  if (i >= 4096) return;
  int co = i >> 6, k = i & 63;
  float v = (k < 48) ? ld_any(src, co * 48 + k, *flag) : 0.f;
  dst[i] = __float2bfloat16(v);
}

// weights OIHW [CO][CI][4][4] -> [tap=kh*4+kw][co][ci] bf16
template <int CO, int CI>
__global__ void rp_conv_w(const void* __restrict__ src, bf16* __restrict__ dst,
                          const int* __restrict__ flag) {
  const int N = CO * CI * 16;
  int i = blockIdx.x * blockDim.x + threadIdx.x;
  if (i >= N) return;
  int co = i / (CI * 16);
  int rem = i % (CI * 16);
  int ci = rem >> 4;
  int k = rem & 15;
  dst[((long)k * CO + co) * CI + ci] = __float2bfloat16(ld_any(src, i, *flag));
}

// convT weights [CI][CO][4][4] -> [class pq][tap st][co][ci] bf16
template <int CI, int CO>
__global__ void rp_convt_w(const void* __restrict__ src, bf16* __restrict__ dst,
                           const int* __restrict__ flag) {
  const int N = CI * CO * 16;
  int i = blockIdx.x * blockDim.x + threadIdx.x;
  if (i >= N) return;
  int ci = i / (CO * 16);
  int rem = i % (CO * 16);
  int co = rem >> 4;
  int k = rem & 15;
  int kh = k >> 2, kw = k & 3;
  int p = (kh + 1) & 1, s = (kh - 1 + p) >> 1;
  int q = (kw + 1) & 1, t = (kw - 1 + q) >> 1;
  long d = (((long)(p * 2 + q) * 4 + (s * 2 + t)) * CO + co) * CI + ci;
  dst[d] = __float2bfloat16(ld_any(src, i, *flag));
}

// [tg][co][ci] -> fragment order [((tg*MC+mc)*KC+kc)*2+j][ln][quad*8]
template <int MC, int KC>
__global__ void frag_pack(const bf16* __restrict__ src, bf16* __restrict__ dst, int total) {
  int i = blockIdx.x * 256 + threadIdx.x;
  if (i >= total) return;
  int low = i & 511;
  int ln = low >> 5, cl = low & 31;
  int c2 = i >> 9;
  int j = c2 & 1;
  int c3 = c2 >> 1;
  int kc = c3 & (KC - 1);
  int c4 = c3 / KC;
  int mc = c4 & (MC - 1);
  int tg = c4 / MC;
  int co = mc * 32 + j * 16 + ln;
  int ci = kc * 32 + cl;
  dst[i] = src[((long)tg * (MC * 32) + co) * (KC * 32) + ci];
}

// d1 weights [256ci][64co][4][4] -> frag [(((cls*4+t)*8+kc)*4+j)][ln][quad*8]
__global__ void rp_d1f(const void* __restrict__ src, bf16* __restrict__ dst,
                       const int* __restrict__ flag) {
  int i = blockIdx.x * 256 + threadIdx.x;   // 262144
  if (i >= 262144) return;
  int low = i & 511;
  int ln = low >> 5, cl = low & 31;
  int c2 = i >> 9;
  int j = c2 & 3;
  int kc = (c2 >> 2) & 7;
  int t = (c2 >> 5) & 3;
  int cls = c2 >> 7;
  int p = cls >> 1, q = cls & 1;
  int s = t >> 1, t2 = t & 1;
  int kh = 2 * s + 1 - p, kw = 2 * t2 + 1 - q;
  int co = j * 16 + ln, ci = kc * 32 + cl;
  dst[i] = __float2bfloat16(ld_any(src, (long)ci * 1024 + co * 16 + kh * 4 + kw, *flag));
}

// final convT weights [64ci][3co][4][4] -> A[m=cls*4+co][d=dy*3+dx][64ci]
__global__ void rp_finw(const void* __restrict__ src, bf16* __restrict__ dst,
                        const int* __restrict__ flag) {
  int i = blockIdx.x * blockDim.x + threadIdx.x;   // 16*576 = 9216
  if (i >= 9216) return;
  int m = i / 576, rem = i % 576;
  int d = rem >> 6, ci = rem & 63;
  int cls = m >> 2, co = m & 3;
  int p = cls >> 1, q = cls & 1;
  int dy = d / 3, dx = d % 3;
  int s = p - dy + 1, t = q - dx + 1;
  float v = 0.f;
  if (co < 3 && s >= 0 && s <= 1 && t >= 0 && t <= 1) {
    int kh = 2 * s + 1 - p, kw = 2 * t + 1 - q;
    v = ld_any(src, ci * 48 + co * 16 + kh * 4 + kw, *flag);
  }
  dst[i] = __float2bfloat16(v);
}

// -------------------- conv1 as GEMM: im2col (K padded to 64) + MFMA GEMM
__global__ __launch_bounds__(256) void im2col1(const void* __restrict__ x,
                                               const int* __restrict__ flag,
                                               bf16* __restrict__ col) {
  int tid = blockIdx.x * 256 + threadIdx.x;   // 16*128*128
  int ow = tid & 127; int t = tid >> 7;
  int oh = t & 127; int b = t >> 7;
  int fl = *flag;
  int ih0 = oh * 2 - 1, iw0 = ow * 2 - 1;
  unsigned short vals[64];
  #pragma unroll
  for (int j = 48; j < 64; ++j) vals[j] = 0;
  #pragma unroll
  for (int ci = 0; ci < 3; ++ci) {
    long pbase = ((long)(b * 3 + ci)) << 16;
    #pragma unroll
    for (int kh = 0; kh < 4; ++kh) {
      int ih = ih0 + kh;
      bool okh = (unsigned)ih < 256u;
      long rbase = pbase + ((long)ih << 8);
      #pragma unroll
      for (int kw = 0; kw < 4; ++kw) {
        int iw = iw0 + kw;
        float v = (okh && (unsigned)iw < 256u) ? ld_any(x, rbase + iw, fl) : 0.f;
        vals[ci * 16 + kh * 4 + kw] = f2bfbits(v);
      }
    }
  }
  uint4* dst = (uint4*)(col + (long)tid * 64);
  const uint4* s = (const uint4*)vals;
  #pragma unroll
  for (int j = 0; j < 8; ++j) dst[j] = s[j];
}

// M=64 (co), K=64, N=262144; bias+relu; store parity-split padded NHWC
__global__ __launch_bounds__(256) void gemm1(const bf16* __restrict__ col,
                                             const bf16* __restrict__ w,
                                             const float* __restrict__ bias,
                                             bf16* __restrict__ act1p) {
  const int lane = threadIdx.x & 63, wv = threadIdx.x >> 6;
  const int wm = wv & 1, wn = wv >> 1;
  const int ln = lane & 15, quad = lane >> 4;
  const int n0 = blockIdx.x * 128 + wn * 64;
  float4v acc[2][4];
  #pragma unroll
  for (int i = 0; i < 2; ++i)
    #pragma unroll
    for (int j = 0; j < 4; ++j) acc[i][j] = {0.f, 0.f, 0.f, 0.f};
  #pragma unroll
  for (int kc = 0; kc < 2; ++kc) {
    const bf16* wk = w + (wm * 32 + ln) * 64 + kc * 32 + quad * 8;
    short8 a0 = *(const short8*)(wk);
    short8 a1 = *(const short8*)(wk + 16 * 64);
    #pragma unroll
    for (int bf = 0; bf < 4; ++bf) {
      short8 bv = *(const short8*)(col + (long)(n0 + bf * 16 + ln) * 64 + kc * 32 + quad * 8);
      acc[0][bf] = __builtin_amdgcn_mfma_f32_16x16x32_bf16(a0, bv, acc[0][bf], 0, 0, 0);
      acc[1][bf] = __builtin_amdgcn_mfma_f32_16x16x32_bf16(a1, bv, acc[1][bf], 0, 0, 0);
    }
  }
  #pragma unroll
  for (int mf = 0; mf < 2; ++mf) {
    int coB = wm * 32 + mf * 16 + quad * 4;
    float4v bv4 = *(const float4v*)(bias + coB);
    #pragma unroll
    for (int bf = 0; bf < 4; ++bf) {
      int n = n0 + bf * 16 + ln;
      int ow = n & 127; int t2 = n >> 7;
      int oh = t2 & 127; int b = t2 >> 7;
      int xx = ow + 1;   // parity-split column
      long oaddr = ((long)(b * 130 + oh + 1)) * 8320 +
                   (long)(((xx & 1) * 65) + (xx >> 1)) * 64 + coB;
      float4v v = acc[mf][bf];
      ushort4v o;
      #pragma unroll
      for (int e = 0; e < 4; ++e) o[e] = f2bfbits(fmaxf(v[e] + bv4[e], 0.f));
      *(ushort4v*)(act1p + oaddr) = o;
    }
  }
}

// ------------------------------------------- MFMA implicit-GEMM tap conv
template <int COUT, int CINT, int TC, int S, int NT, int INC, int NBF, int PXW>
__global__ __launch_bounds__(256) void mfma_conv(
    const bf16* __restrict__ in1, const bf16* __restrict__ in2,
    long inImgS, int inRowS,
    const bf16* __restrict__ wf, const float* __restrict__ bias,
    bf16* __restrict__ outp, long outImgS, int oRS, int oCS,
    int nxb, long po, long qo, int oPXW) {
  constexpr int TR = (2 * NBF * 16) / TC;
  constexpr int KC = CINT / 32;
  constexpr int MC = COUT / 32;
  constexpr int KSPLIT = (CINT > INC) ? (INC / 32) : KC;
  const int lane = threadIdx.x & 63;
  const int wv = threadIdx.x >> 6;
  const int wm = wv & 1, wn = wv >> 1;
  const int ln = lane & 15, quad = lane >> 4;
  const int cls = blockIdx.x >> nxb;
  const int xb = blockIdx.x & ((1u << nxb) - 1u);
  const int mTile = blockIdx.y * 64;
  const int mc = blockIdx.y * 2 + wm;
  const int oh0 = xb * TR;
  const int b = blockIdx.z;
  const int p = cls >> 1, q = cls & 1;
  const long ooff = (long)(p + 1) * po + (long)(q + 1) * qo;

  long posOff[NBF];
  int rr[NBF], cc[NBF];
  #pragma unroll
  for (int bf = 0; bf < NBF; ++bf) {
    int n = wn * (NBF * 16) + bf * 16 + ln;
    int r = n / TC, c = n % TC;
    rr[bf] = r; cc[bf] = c;
    posOff[bf] = (long)(S * (oh0 + r)) * inRowS +
                 (PXW ? (long)c * INC : (long)(S * c) * INC);
  }
  const bf16* inb1 = in1 + (long)b * inImgS;
  const bf16* inb2 = in2 + (long)b * inImgS;

  float4v acc[2][NBF];
  #pragma unroll
  for (int i = 0; i < 2; ++i)
    #pragma unroll
    for (int j = 0; j < NBF; ++j) acc[i][j] = {0.f, 0.f, 0.f, 0.f};

  for (int t = 0; t < NT; ++t) {
    int dy, dx;
    if (S == 2) { dy = t >> 2; dx = t & 3; }
    else        { dy = p - (t >> 1) + 1; dx = q - (t & 1) + 1; }
    const int dxo = PXW ? ((dx & 1) * PXW + (dx >> 1)) : dx;
    const long tapOff = (long)dy * inRowS + (long)dxo * INC;
    const bf16* wt = wf + ((long)(cls * NT + t) * MC + mc) * (KC * 1024) + ln * 32 + quad * 8;
    #pragma unroll
    for (int kc = 0; kc < KC; ++kc) {
      short8 a0 = *(const short8*)(wt + kc * 1024);
      short8 a1 = *(const short8*)(wt + kc * 1024 + 512);
      const bf16* bp = (kc < KSPLIT) ? inb1 : inb2;
      int kOff = (kc < KSPLIT ? kc : kc - KSPLIT) * 32 + quad * 8;
      #pragma unroll
      for (int bf = 0; bf < NBF; ++bf) {
        short8 bv = *(const short8*)(bp + posOff[bf] + tapOff + kOff);
        acc[0][bf] = __builtin_amdgcn_mfma_f32_16x16x32_bf16(a0, bv, acc[0][bf], 0, 0, 0);
        acc[1][bf] = __builtin_amdgcn_mfma_f32_16x16x32_bf16(a1, bv, acc[1][bf], 0, 0, 0);
      }
    }
  }

  bf16* outb = outp + (long)b * outImgS + ooff;
  #pragma unroll
  for (int mf = 0; mf < 2; ++mf) {
    int coB = mTile + wm * 32 + mf * 16 + quad * 4;
    float4v bv4 = *(const float4v*)(bias + coB);
    #pragma unroll
    for (int bf = 0; bf < NBF; ++bf) {
      float4v v = acc[mf][bf];
      ushort4v o;
      #pragma unroll
      for (int e = 0; e < 4; ++e)
        o[e] = f2bfbits(fmaxf(v[e] + bv4[e], 0.f));
      long coff = oPXW ? (long)((((cc[bf] + 1) & 1) * oPXW) + ((cc[bf] + 1) >> 1)) * oCS
                       : (long)cc[bf] * oCS;
      long oaddr = (long)(oh0 + rr[bf]) * oRS + coff + oCS * 0 + coB;
      *(ushort4v*)(outb + oaddr) = o;
    }
  }
}

// ---------- conv2 (64 -> 128, s2) with LDS-staged input, wave M64xN64
// Block: 128 threads = 2 waves (wave = co-half), one (img, output row oh).
// Phase f in {0,1}: stage act1p rows 2oh+2f, 2oh+2f+1 (2 contiguous parity
// rows, 2080 chunks) into LDS padded 8->9 chunks/pos; taps dy in {2f,2f+1}.
// Per (t,kc): 4 global A-frags + 4 ds_read B-frags -> 16 MFMA (4:1).
__global__ __launch_bounds__(128) void conv2_lds(
    const bf16* __restrict__ in, const bf16* __restrict__ wf,
    const float* __restrict__ bias, bf16* __restrict__ outp) {
  __shared__ short8 lds8[2 * 130 * 9];   // 37440 B
  const int lane = threadIdx.x & 63;
  const int h = threadIdx.x >> 6;        // co-half (wave id)
  const int ln = lane & 15, quad = lane >> 4;
  const int oh = blockIdx.x;             // output row 0..63
  const int b = blockIdx.z;

  const bf16* img = in + (long)b * 1081600;

  float4v acc[4][4];   // [j4 (co chunk)][bf (pos chunk)]
  #pragma unroll
  for (int j = 0; j < 4; ++j)
    #pragma unroll
    for (int bf = 0; bf < 4; ++bf) acc[j][bf] = {0.f, 0.f, 0.f, 0.f};

  #pragma unroll
  for (int f = 0; f < 2; ++f) {
    const short8* src8 = (const short8*)(img + (long)(2 * oh + 2 * f) * 8320);
    __syncthreads();
    for (int i = threadIdx.x; i < 2080; i += 128) {   // 2 rows x 130 pos x 8
      int pos2 = i >> 3, j = i & 7;                   // pos2 = r*130 + pos
      lds8[pos2 * 9 + j] = src8[i];
    }
    __syncthreads();
    #pragma unroll
    for (int tl = 0; tl < 8; ++tl) {
      const int t = 8 * f + tl;
      const int r = (t >> 2) & 1;        // row within phase
      const int dx = t & 3;
      const int pp = dx & 1, cb = dx >> 1;
      const int lbase = (r * 130 + pp * 65 + cb) * 9 + quad;
      const bf16* wt = wf + (long)(t * 4) * 2048 + (long)(2 * h) * 2048 +
                       ln * 32 + quad * 8;
      #pragma unroll
      for (int kc = 0; kc < 2; ++kc) {
        const bf16* wk = wt + kc * 1024;
        short8 a0 = *(const short8*)(wk);          // mc=2h,   j=0
        short8 a1 = *(const short8*)(wk + 512);    // mc=2h,   j=1
        short8 a2 = *(const short8*)(wk + 2048);   // mc=2h+1, j=0
        short8 a3 = *(const short8*)(wk + 2560);   // mc=2h+1, j=1
        #pragma unroll
        for (int bf = 0; bf < 4; ++bf) {
          short8 bv = lds8[lbase + (bf * 16 + ln) * 9 + kc * 4];
          acc[0][bf] = __builtin_amdgcn_mfma_f32_16x16x32_bf16(a0, bv, acc[0][bf], 0, 0, 0);
          acc[1][bf] = __builtin_amdgcn_mfma_f32_16x16x32_bf16(a1, bv, acc[1][bf], 0, 0, 0);
          acc[2][bf] = __builtin_amdgcn_mfma_f32_16x16x32_bf16(a2, bv, acc[2][bf], 0, 0, 0);
          acc[3][bf] = __builtin_amdgcn_mfma_f32_16x16x32_bf16(a3, bv, acc[3][bf], 0, 0, 0);
        }
      }
    }
  }

  // store: zbp parity layout, row oh+1, col map x -> ((x+1)&1)*33 + ((x+1)>>1)
  bf16* outb = outp + (long)b * 557568 + (long)(oh + 1) * 8448;
  #pragma unroll
  for (int j4 = 0; j4 < 4; ++j4) {
    int co = h * 64 + (j4 >> 1) * 32 + (j4 & 1) * 16 + quad * 4;
    float4v bv4 = *(const float4v*)(bias + co);
    #pragma unroll
    for (int bf = 0; bf < 4; ++bf) {
      int x = bf * 16 + ln;
      int col = (((x + 1) & 1) * 33) + ((x + 1) >> 1);
      float4v v = acc[j4][bf];
      ushort4v o;
      #pragma unroll
      for (int e = 0; e < 4; ++e)
        o[e] = f2bfbits(fmaxf(v[e] + bv4[e], 0.f));
      *(ushort4v*)(outb + (long)col * 128 + co) = o;
    }
  }
}

// ------ d1 (concat 256 -> 64) with LDS-staged input, 4 classes per block
__global__ __launch_bounds__(256) void mfma_d1_lds(
    const bf16* __restrict__ in1, const bf16* __restrict__ in2,
    const bf16* __restrict__ wf, const float* __restrict__ bias,
    bf16* __restrict__ outp) {
  __shared__ short8 lds8[198 * 17];   // 53856 B
  const int lane = threadIdx.x & 63, wv = threadIdx.x >> 6;
  const int ln = lane & 15, quad = lane >> 4;
  const int r = blockIdx.x;          // output class-row 0..63
  const int b = blockIdx.z;
  const int cls = wv, p = cls >> 1, q = cls & 1;

  const bf16* src1 = in1 + (long)b * 557568 + (long)r * 8448;  // rows r..r+2
  const bf16* src2 = in2 + (long)b * 557568 + (long)r * 8448;

  float4v acc[4][4];
  #pragma unroll
  for (int j = 0; j < 4; ++j)
    #pragma unroll
    for (int bf = 0; bf < 4; ++bf) acc[j][bf] = {0.f, 0.f, 0.f, 0.f};

  #pragma unroll
  for (int phase = 0; phase < 2; ++phase) {
    const bf16* src = phase ? src2 : src1;
    __syncthreads();
    for (int i = threadIdx.x; i < 3168; i += 256) {   // 198 pos x 16 chunks
      int pos = i >> 4, j = i & 15;
      lds8[pos * 17 + j] = *(const short8*)(src + (long)pos * 128 + j * 8);
    }
    __syncthreads();
    #pragma unroll
    for (int t = 0; t < 4; ++t) {
      int dy = p - (t >> 1) + 1, dx = q - (t & 1) + 1;
      const bf16* wt = wf + (long)(cls * 4 + t) * 16384 + (long)(phase * 4) * 2048 +
                       ln * 32 + quad * 8;
      const int lbase = (dy * 66 + dx) * 17 + quad;
      #pragma unroll
      for (int kc = 0; kc < 4; ++kc) {
        const bf16* wk = wt + kc * 2048;
        short8 a0 = *(const short8*)(wk);
        short8 a1 = *(const short8*)(wk + 512);
        short8 a2 = *(const short8*)(wk + 1024);
        short8 a3 = *(const short8*)(wk + 1536);
        #pragma unroll
        for (int bf = 0; bf < 4; ++bf) {
          short8 bv = lds8[lbase + kc * 4 + (bf * 16 + ln) * 17];
          acc[0][bf] = __builtin_amdgcn_mfma_f32_16x16x32_bf16(a0, bv, acc[0][bf], 0, 0, 0);
          acc[1][bf] = __builtin_amdgcn_mfma_f32_16x16x32_bf16(a1, bv, acc[1][bf], 0, 0, 0);
          acc[2][bf] = __builtin_amdgcn_mfma_f32_16x16x32_bf16(a2, bv, acc[2][bf], 0, 0, 0);
          acc[3][bf] = __builtin_amdgcn_mfma_f32_16x16x32_bf16(a3, bv, acc[3][bf], 0, 0, 0);
        }
      }
    }
  }

  bf16* outb = outp + (long)b * 1081600 + (long)(p + 1) * 8320 + (long)(q + 1) * 64 +
               (long)r * 16640;
  #pragma unroll
  for (int j = 0; j < 4; ++j) {
    int co = j * 16 + quad * 4;
    float4v bv4 = *(const float4v*)(bias + co);
    #pragma unroll
    for (int bf = 0; bf < 4; ++bf) {
      float4v v = acc[j][bf];
      ushort4v o;
      #pragma unroll
      for (int e = 0; e < 4; ++e)
        o[e] = f2bfbits(fmaxf(v[e] + bv4[e], 0.f));
      *(ushort4v*)(outb + (long)(bf * 16 + ln) * 128 + co) = o;
    }
  }
}

// ---------------------------------------------------- VQ via MFMA GEMM
__global__ __launch_bounds__(256) void vq_mfma(
    const bf16* __restrict__ z, long zImgS, int zRowS,
    const bf16* __restrict__ emb, const float* __restrict__ embsq,
    bf16* __restrict__ zq, long qImgS, int qRowS,
    float* __restrict__ loss_acc, int wb, int hwb, int ipxw) {
  const int lane = threadIdx.x & 63, wv = threadIdx.x >> 6;
  const int ln = lane & 15, quad = lane >> 4;
  const int base = blockIdx.x * 256 + wv * 64;

  short8 bfrag[4][4];
  #pragma unroll
  for (int bf = 0; bf < 4; ++bf) {
    int n = base + bf * 16 + ln;
    int b = n >> hwb;
    int rem = n & ((1 << hwb) - 1);
    int y = rem >> wb, x = rem & ((1 << wb) - 1);
    int xcol = ipxw ? ((((x + 1) & 1) * ipxw) + ((x + 1) >> 1)) : x;
    const bf16* zrow = z + (long)b * zImgS + (long)y * zRowS + (long)xcol * 128;
    #pragma unroll
    for (int kc = 0; kc < 4; ++kc)
      bfrag[bf][kc] = *(const short8*)(zrow + kc * 32 + quad * 8);
  }

  float best0 = 3.4e38f, best1 = 3.4e38f, best2 = 3.4e38f, best3 = 3.4e38f;
  int bk0 = 0, bk1 = 0, bk2 = 0, bk3 = 0;
  for (int ct = 0; ct < 32; ++ct) {
    const bf16* erow = emb + (long)(ct * 16 + ln) * 128 + quad * 8;
    short8 a0 = *(const short8*)(erow);
    short8 a1 = *(const short8*)(erow + 32);
    short8 a2 = *(const short8*)(erow + 64);
    short8 a3 = *(const short8*)(erow + 96);
    float4v sq4 = *(const float4v*)(embsq + ct * 16 + quad * 4);
    #pragma unroll
    for (int bf = 0; bf < 4; ++bf) {
      float4v acc = {0.f, 0.f, 0.f, 0.f};
      acc = __builtin_amdgcn_mfma_f32_16x16x32_bf16(a0, bfrag[bf][0], acc, 0, 0, 0);
      acc = __builtin_amdgcn_mfma_f32_16x16x32_bf16(a1, bfrag[bf][1], acc, 0, 0, 0);
      acc = __builtin_amdgcn_mfma_f32_16x16x32_bf16(a2, bfrag[bf][2], acc, 0, 0, 0);
      acc = __builtin_amdgcn_mfma_f32_16x16x32_bf16(a3, bfrag[bf][3], acc, 0, 0, 0);
      int kb = ct * 16 + quad * 4;
      #pragma unroll
      for (int r = 0; r < 4; ++r) {
        float s = fmaf(-2.f, acc[r], sq4[r]);
        if (bf == 0) { if (s < best0) { best0 = s; bk0 = kb + r; } }
        if (bf == 1) { if (s < best1) { best1 = s; bk1 = kb + r; } }
        if (bf == 2) { if (s < best2) { best2 = s; bk2 = kb + r; } }
        if (bf == 3) { if (s < best3) { best3 = s; bk3 = kb + r; } }
      }
    }
  }
  float bs[4] = {best0, best1, best2, best3};
  int bk[4] = {bk0, bk1, bk2, bk3};
  #pragma unroll
  for (int bf = 0; bf < 4; ++bf) {
    #pragma unroll
    for (int m = 16; m <= 32; m <<= 1) {
      float os = __shfl_xor(bs[bf], m, 64);
      int ok = __shfl_xor(bk[bf], m, 64);
      if (os < bs[bf] || (os == bs[bf] && ok < bk[bf])) { bs[bf] = os; bk[bf] = ok; }
    }
  }
  int myk = (quad == 0) ? bk[0] : (quad == 1) ? bk[1] : (quad == 2) ? bk[2] : bk[3];
  int n = base + quad * 16 + ln;
  int b = n >> hwb;
  int rem = n & ((1 << hwb) - 1);
  int y = rem >> wb, x = rem & ((1 << wb) - 1);
  int xcol = ipxw ? ((((x + 1) & 1) * ipxw) + ((x + 1) >> 1)) : x;
  const uint4* zr = (const uint4*)(z + (long)b * zImgS + (long)y * zRowS + (long)xcol * 128);
  uint4* qr = (uint4*)(zq + (long)b * qImgS + (long)y * qRowS + (long)x * 128);
  const uint4* er = (const uint4*)(emb + (long)myk * 128);
  float lsum = 0.f;
  #pragma unroll
  for (int j = 0; j < 16; ++j) {
    uint4 ue = er[j];
    uint4 uz = zr[j];
    qr[j] = ue;
    float ev[8], zv[8];
    unpack_u4(ue, ev);
    unpack_u4(uz, zv);
    #pragma unroll
    for (int e = 0; e < 8; ++e) {
      float dv = ev[e] - zv[e];
      lsum = fmaf(dv, dv, lsum);
    }
  }
  for (int o = 32; o > 0; o >>= 1) lsum += __shfl_down(lsum, o, 64);
  if (lane == 0) atomicAdd(loss_acc, lsum);
}

// --------------------- final convT(64->3)+sigmoid via class-packed MFMA
__global__ __launch_bounds__(256) void final_convt_mfma(
    const bf16* __restrict__ hp, const bf16* __restrict__ wfin,
    const float* __restrict__ bf_, float* __restrict__ out) {
  const int lane = threadIdx.x & 63, wv = threadIdx.x >> 6;
  const int ln = lane & 15, quad = lane >> 4;
  const int base = blockIdx.x * 256 + wv * 64;   // 262144 positions total

  short8 afr[18];
  #pragma unroll
  for (int kc = 0; kc < 18; ++kc)
    afr[kc] = *(const short8*)(wfin + ln * 576 + kc * 32 + quad * 8);

  float4v acc[4];
  #pragma unroll
  for (int bf = 0; bf < 4; ++bf) acc[bf] = {0.f, 0.f, 0.f, 0.f};

  #pragma unroll
  for (int bf = 0; bf < 4; ++bf) {
    int n = base + bf * 16 + ln;
    int xx = n & 127, y = (n >> 7) & 127, b = n >> 14;
    const bf16* hb = hp + (long)b * 1081600 + (long)y * 8320 + (long)xx * 64;
    #pragma unroll
    for (int kc = 0; kc < 18; ++kc) {
      int d = kc >> 1;
      const bf16* bp = hb + (long)(d / 3) * 8320 + (d % 3) * 64 + (kc & 1) * 32 + quad * 8;
      short8 bv = *(const short8*)bp;
      acc[bf] = __builtin_amdgcn_mfma_f32_16x16x32_bf16(afr[kc], bv, acc[bf], 0, 0, 0);
    }
  }

  const int p = quad >> 1, q = quad & 1;
  float b0 = bf_[0], b1 = bf_[1], b2 = bf_[2];
  #pragma unroll
  for (int bf = 0; bf < 4; ++bf) {
    int n = base + bf * 16 + ln;
    int xx = n & 127, y = (n >> 7) & 127, b = n >> 14;
    long ob = (long)b * 196608 + (long)(2 * y + p) * 256 + (2 * xx + q);
    float v0 = acc[bf][0] + b0, v1 = acc[bf][1] + b1, v2 = acc[bf][2] + b2;
    out[ob]          = 1.f / (1.f + expf(-v0));
    out[ob + 65536]  = 1.f / (1.f + expf(-v1));
    out[ob + 131072] = 1.f / (1.f + expf(-v2));
  }
}

__global__ void finalize_loss_kernel(const float* __restrict__ lacc, float* __restrict__ out) {
  if (threadIdx.x == 0) {
    float lt = lacc[0] * (1.5f / 2097152.f);
    float lb = lacc[1] * (1.5f / 8388608.f);
    *out = lt + lb;
  }
}

// ------------------------------------------------------------------ launch
extern "C" void kernel_launch(void* const* d_in, const int* in_sizes, int n_in,
                              void* d_out, int out_size, void* d_ws, size_t ws_size,
                              hipStream_t stream) {
  float* out = (float*)d_out;
  char* base = (char*)d_ws;
  size_t off = 0;
  auto alloc = [&](size_t bytes) {
    void* pp = base + off;
    off = (off + bytes + 255) & ~(size_t)255;
    return pp;
  };

  int* flag = (int*)alloc(256);
  float* biasAll = (float*)alloc(515 * 4);
  float* beB1f = biasAll + 0;
  float* beB2f = biasAll + 64;
  float* beTf  = biasAll + 192;
  float* bdTf  = biasAll + 320;
  float* bd1f  = biasAll + 448;
  float* bd2f  = biasAll + 512;
  float* sqAll = (float*)alloc(1024 * 4);
  float* sqT = sqAll, *sqB = sqAll + 512;
  float* lacc = (float*)alloc(2 * 4);
  bf16* Wc1  = (bf16*)alloc((size_t)4096 * 2);
  bf16* Wt2  = (bf16*)alloc((size_t)131072 * 2);
  bf16* Wtt  = (bf16*)alloc((size_t)262144 * 2);
  bf16* Wdt  = (bf16*)alloc((size_t)262144 * 2);
  bf16* Wt2f = (bf16*)alloc((size_t)131072 * 2);
  bf16* Wttf = (bf16*)alloc((size_t)262144 * 2);
  bf16* Wdtf = (bf16*)alloc((size_t)262144 * 2);
  bf16* Wd1f = (bf16*)alloc((size_t)262144 * 2);
  bf16* Wfin = (bf16*)alloc((size_t)9216 * 2);
  bf16* embTB = (bf16*)alloc((size_t)131072 * 2);
  bf16* embT = embTB, *embB = embTB + 65536;
  bf16* colb = (bf16*)alloc((size_t)16777216 * 2);   // im2col [262144][64]
  bf16* act1p = (bf16*)alloc((size_t)17305600 * 2);  // [16][130][2][65][64] parity
  bf16* zbp   = (bf16*)alloc((size_t)8921088 * 2);   // [16][66][2][33][128] parity
  bf16* zqtp  = (bf16*)alloc((size_t)2367488 * 2);   // [16][34][34][128]
  bf16* eup   = (bf16*)alloc((size_t)8921088 * 2);   // [16][66][66][128]
  bf16* fqp   = (bf16*)alloc((size_t)8921088 * 2);   // [16][66][66][128]
  bf16* hp    = (bf16*)alloc((size_t)17305600 * 2);  // [16][130][130][64]
  bf16* ztp   = (bf16*)alloc((size_t)2097152 * 2);   // [16][32][32][128]

  detect_dtype_kernel<<<1, 256, 0, stream>>>(d_in[0], flag);
  zero2_kernel<<<1, 64, 0, stream>>>(lacc);

  // halo-only zeroing (edge offsets identical in parity-split layout)
  zero_halo<<<517, 256, 0, stream>>>(act1p, hp, nullptr, 2, 130, 130, 8, 1081600, 16, 4128);
  zero_halo<<<781, 256, 0, stream>>>(zbp, eup, fqp, 3, 66, 66, 16, 557568, 16, 4160);
  zero_halo<<<132, 256, 0, stream>>>(zqtp, nullptr, nullptr, 1, 34, 34, 16, 147968, 16, 2112);

  // converts / repacks
  conv_bias_all<<<3, 256, 0, stream>>>(d_in[2], d_in[4], d_in[6], d_in[10],
                                       d_in[12], d_in[14], biasAll, flag);
  conv_emb<<<512, 256, 0, stream>>>(d_in[7], d_in[8], embTB, flag);
  embsq2<<<4, 256, 0, stream>>>(embTB, sqAll);
  rp_c1w<<<16, 256, 0, stream>>>(d_in[1], Wc1, flag);
  rp_conv_w<128, 64><<<512, 256, 0, stream>>>(d_in[3], Wt2, flag);
  rp_conv_w<128, 128><<<1024, 256, 0, stream>>>(d_in[5], Wtt, flag);
  rp_convt_w<128, 128><<<1024, 256, 0, stream>>>(d_in[9], Wdt, flag);
  rp_d1f<<<1024, 256, 0, stream>>>(d_in[11], Wd1f, flag);
  rp_finw<<<36, 256, 0, stream>>>(d_in[13], Wfin, flag);
  frag_pack<4, 2><<<512, 256, 0, stream>>>(Wt2, Wt2f, 131072);
  frag_pack<4, 4><<<1024, 256, 0, stream>>>(Wtt, Wttf, 262144);
  frag_pack<4, 4><<<1024, 256, 0, stream>>>(Wdt, Wdtf, 262144);

  // encoder: conv1 = im2col + MFMA GEMM (parity-split store)
  im2col1<<<1024, 256, 0, stream>>>(d_in[0], flag, colb);
  gemm1<<<2048, 256, 0, stream>>>(colb, Wc1, beB1f, act1p);
  // conv2: LDS-staged, wave M64xN64, 1024 blocks x 128 threads
  conv2_lds<<<dim3(64, 1, 16), 128, 0, stream>>>(act1p, Wt2f, beB2f, zbp);
  // conv_t: PXW=33 (zbp parity), output ztp row-major
  mfma_conv<128, 128, 32, 2, 16, 128, 2, 33><<<dim3(16, 2, 16), 256, 0, stream>>>(
      zbp, zbp, 557568, 8448, Wttf, beTf, ztp, 131072, 4096, 128, 30, 0, 0, 0);

  // VQ top (16384 positions, row-major)
  vq_mfma<<<64, 256, 0, stream>>>(ztp, 131072, 4096, embT, sqT,
                                  zqtp + 4480, 147968, 4352, lacc + 0, 5, 10, 0);

  // decoder_top upsample: 4 classes in one launch (row-major in/out)
  mfma_conv<128, 128, 32, 1, 4, 128, 2, 0><<<dim3(64, 2, 16), 256, 0, stream>>>(
      zqtp, zqtp, 147968, 4352, Wdtf, bdTf, eup, 557568, 16896, 256, 4, 8448, 128, 0);

  // VQ bottom (65536 positions; zbp parity-split input, fqp row-major out)
  vq_mfma<<<256, 256, 0, stream>>>(zbp + 8448, 557568, 8448, embB, sqB,
                                   fqp + 8576, 557568, 8448, lacc + 1, 6, 12, 33);

  // decoder conv d1: LDS-staged, 4 classes per block, 1024 blocks
  mfma_d1_lds<<<dim3(64, 1, 16), 256, 0, stream>>>(fqp, eup, Wd1f, bd1f, hp);

  // final convT + sigmoid via MFMA -> fp32 NCHW output
  final_convt_mfma<<<1024, 256, 0, stream>>>(hp, Wfin, bd2f, out);
  finalize_loss_kernel<<<1, 64, 0, stream>>>(lacc, out + 3145728);
}